// Round 2
// baseline (248.765 us; speedup 1.0000x reference)
//
#include <hip/hip_runtime.h>
#include <hip/hip_bf16.h>
#include <stdint.h>

#define SDIM 1024
#define BATCH 4
#define NH 16
#define HDIM 64
#define KDIM 1024
#define N_QKV 3072
#define EMB 1024

typedef uint16_t u16;
typedef __attribute__((ext_vector_type(4))) float f32x4;
typedef __attribute__((ext_vector_type(8))) short bf16x8;
typedef __attribute__((ext_vector_type(8))) unsigned short u16x8;

__device__ __forceinline__ u16 f2bf(float f) {
  union { float f; uint32_t u; } x; x.f = f;
  uint32_t r = x.u + 0x7FFFu + ((x.u >> 16) & 1u);
  return (u16)(r >> 16);
}

__device__ __forceinline__ float bf2f(u16 b) {
  union { uint32_t u; float f; } x; x.u = ((uint32_t)b) << 16;
  return x.f;
}

__device__ __forceinline__ void gload_lds16(const u16* g, u16* l) {
  __builtin_amdgcn_global_load_lds(
      (const __attribute__((address_space(1))) unsigned int*)g,
      (__attribute__((address_space(3))) unsigned int*)l, 16, 0, 0);
}

// ---------------- f32 -> bf16 conversion (memory-bound) ----------------
__global__ void cvt_bf16_kernel(const float* __restrict__ src, u16* __restrict__ dst, int n8) {
  int stride = gridDim.x * blockDim.x;
  for (int i = blockIdx.x * blockDim.x + threadIdx.x; i < n8; i += stride) {
    const float4* s4 = (const float4*)src + (size_t)i * 2;
    float4 a = s4[0], b = s4[1];
    u16x8 o;
    o[0] = f2bf(a.x); o[1] = f2bf(a.y); o[2] = f2bf(a.z); o[3] = f2bf(a.w);
    o[4] = f2bf(b.x); o[5] = f2bf(b.y); o[6] = f2bf(b.z); o[7] = f2bf(b.w);
    ((u16x8*)dst)[i] = o;
  }
}

// ---------------- wm[b][k][q] = mask[b][q][k] ? weights[b][k][q] : 0  (bf16) ----------------
__global__ __launch_bounds__(256) void wm_kernel(
    const int* __restrict__ mask, const float* __restrict__ wts, u16* __restrict__ wm)
{
  __shared__ int mt[64][65];
  const int b = blockIdx.z;
  const int k0 = blockIdx.x * 64, q0 = blockIdx.y * 64;
  const int tx = threadIdx.x & 63, ty = threadIdx.x >> 6;
  const size_t SS = (size_t)SDIM * SDIM;
  const int* mrow = mask + (size_t)b * SS + (size_t)q0 * SDIM + k0;
  #pragma unroll
  for (int i = 0; i < 16; ++i) {
    int qr = i * 4 + ty;
    mt[tx][qr] = mrow[(size_t)qr * SDIM + tx];   // coalesced read, transposed store
  }
  __syncthreads();
  const float* wrow = wts + (size_t)b * SS + (size_t)k0 * SDIM + q0;
  u16* orow = wm + (size_t)b * SS + (size_t)k0 * SDIM + q0;
  #pragma unroll
  for (int i = 0; i < 16; ++i) {
    int kr = i * 4 + ty;
    float w = wrow[(size_t)kr * SDIM + tx];
    orow[(size_t)kr * SDIM + tx] = f2bf(mt[kr][tx] ? w : 0.f);
  }
}

// ---------------- GEMM1: qkv projection, routed epilogue ----------------
// A[M][K], B[N][K]^T bf16; writes Qh[b][h][s][d] (pre-scaled by 1/8), Kh[b][h][s][d], Vt[b][h][d][s]
__global__ __launch_bounds__(256) void gemm_qkv(
    const u16* __restrict__ A, const u16* __restrict__ Bm,
    const float* __restrict__ bias,
    u16* __restrict__ Qh, u16* __restrict__ Kh, u16* __restrict__ Vt)
{
  __shared__ u16 As[128 * 64];
  __shared__ u16 Bs[128 * 64];
  const int tid = threadIdx.x;
  const int wid = tid >> 6, lane = tid & 63;
  const int g = lane >> 4, c = lane & 15;
  const int wrow = (wid >> 1) * 64, wcol = (wid & 1) * 64;
  const int brow = blockIdx.x * 128, bcol = blockIdx.y * 128;
  const int K = KDIM, N = N_QKV;

  f32x4 acc[4][4] = {};

  for (int kt = 0; kt < K / 64; ++kt) {
    #pragma unroll
    for (int j = 0; j < 4; ++j) {
      int ci = j * 256 + tid;
      int r = ci >> 3, c8 = ci & 7;
      gload_lds16(A  + (size_t)(brow + r) * K + kt * 64 + c8 * 8,
                  As + (size_t)(j * 256 + wid * 64) * 8);
      gload_lds16(Bm + (size_t)(bcol + r) * K + kt * 64 + c8 * 8,
                  Bs + (size_t)(j * 256 + wid * 64) * 8);
    }
    __syncthreads();

    bf16x8 af[2][4], bfr[2][4];
    #pragma unroll
    for (int kk = 0; kk < 2; ++kk)
      #pragma unroll
      for (int i = 0; i < 4; ++i) {
        af[kk][i]  = *(const bf16x8*)&As[(wrow + i * 16 + c) * 64 + kk * 32 + g * 8];
        bfr[kk][i] = *(const bf16x8*)&Bs[(wcol + i * 16 + c) * 64 + kk * 32 + g * 8];
      }
    #pragma unroll
    for (int kk = 0; kk < 2; ++kk)
      #pragma unroll
      for (int mi = 0; mi < 4; ++mi)
        #pragma unroll
        for (int ni = 0; ni < 4; ++ni)
          acc[mi][ni] = __builtin_amdgcn_mfma_f32_16x16x32_bf16(
              af[kk][mi], bfr[kk][ni], acc[mi][ni], 0, 0, 0);
    __syncthreads();
  }

  #pragma unroll
  for (int mi = 0; mi < 4; ++mi) {
    #pragma unroll
    for (int ni = 0; ni < 4; ++ni) {
      int col = bcol + wcol + ni * 16 + c;
      float bv = bias[col];
      int h = col / 192;
      int rem = col - h * 192;
      int sec = rem >> 6, d = rem & 63;
      #pragma unroll
      for (int r = 0; r < 4; ++r) {
        int row = brow + wrow + mi * 16 + g * 4 + r;
        int b = row >> 10, sl = row & 1023;
        float v = acc[mi][ni][r] + bv;
        if (sec == 0)
          Qh[((size_t)(b * NH + h) * SDIM + sl) * HDIM + d] = f2bf(v * 0.125f);
        else if (sec == 1)
          Kh[((size_t)(b * NH + h) * SDIM + sl) * HDIM + d] = f2bf(v);
        else
          Vt[((size_t)(b * NH + h) * HDIM + d) * SDIM + sl] = f2bf(v);
      }
    }
  }
}

// ---------------- GEMM2: C[M][N] f32 = A[M][K]*B[N][K]^T + bias ----------------
__global__ __launch_bounds__(256) void gemm_bt(
    const u16* __restrict__ A, const u16* __restrict__ Bm,
    const float* __restrict__ bias, float* __restrict__ C,
    int M, int N, int K)
{
  __shared__ u16 As[128 * 64];
  __shared__ u16 Bs[128 * 64];
  const int tid = threadIdx.x;
  const int wid = tid >> 6, lane = tid & 63;
  const int g = lane >> 4, c = lane & 15;
  const int wrow = (wid >> 1) * 64, wcol = (wid & 1) * 64;
  const int brow = blockIdx.x * 128, bcol = blockIdx.y * 128;

  f32x4 acc[4][4] = {};

  for (int kt = 0; kt < K / 64; ++kt) {
    #pragma unroll
    for (int j = 0; j < 4; ++j) {
      int ci = j * 256 + tid;
      int r = ci >> 3, c8 = ci & 7;
      gload_lds16(A  + (size_t)(brow + r) * K + kt * 64 + c8 * 8,
                  As + (size_t)(j * 256 + wid * 64) * 8);
      gload_lds16(Bm + (size_t)(bcol + r) * K + kt * 64 + c8 * 8,
                  Bs + (size_t)(j * 256 + wid * 64) * 8);
    }
    __syncthreads();

    bf16x8 af[2][4], bfr[2][4];
    #pragma unroll
    for (int kk = 0; kk < 2; ++kk)
      #pragma unroll
      for (int i = 0; i < 4; ++i) {
        af[kk][i]  = *(const bf16x8*)&As[(wrow + i * 16 + c) * 64 + kk * 32 + g * 8];
        bfr[kk][i] = *(const bf16x8*)&Bs[(wcol + i * 16 + c) * 64 + kk * 32 + g * 8];
      }
    #pragma unroll
    for (int kk = 0; kk < 2; ++kk)
      #pragma unroll
      for (int mi = 0; mi < 4; ++mi)
        #pragma unroll
        for (int ni = 0; ni < 4; ++ni)
          acc[mi][ni] = __builtin_amdgcn_mfma_f32_16x16x32_bf16(
              af[kk][mi], bfr[kk][ni], acc[mi][ni], 0, 0, 0);
    __syncthreads();
  }

  #pragma unroll
  for (int mi = 0; mi < 4; ++mi)
    #pragma unroll
    for (int ni = 0; ni < 4; ++ni) {
      int col = bcol + wcol + ni * 16 + c;
      float bv = bias[col];
      #pragma unroll
      for (int r = 0; r < 4; ++r) {
        int row = brow + wrow + mi * 16 + g * 4 + r;
        C[(size_t)row * N + col] = acc[mi][ni][r] + bv;
      }
    }
}

// ---------------- attention: barrier-free, no max-tracking ----------------
// Qh/Kh [bh][s][64] bf16 (Q pre-scaled 1/8), Vt [bh][64][s] bf16, wm [b][k][q] bf16
__global__ __launch_bounds__(256, 4) void attn_kernel(
    const u16* __restrict__ Qh, const u16* __restrict__ Kh, const u16* __restrict__ Vt,
    const u16* __restrict__ wm, u16* __restrict__ vals)
{
  // XCD-chunked swizzle: 1024 blocks -> each XCD gets contiguous 128-run
  int bid = blockIdx.x;
  int swz = (bid & 7) * 128 + (bid >> 3);
  const int qt = swz & 15, bh = swz >> 4;
  const int h = bh & 15, b = bh >> 4;

  const int tid = threadIdx.x;
  const int wid = tid >> 6, lane = tid & 63;
  const int g = lane >> 4, c = lane & 15;
  const int qloc = qt * 64 + wid * 16;

  __shared__ u16 Plds[4][16 * 72];           // per-wave P tile, XOR-swizzled
  char* pw = (char*)&Plds[wid][0];

  const u16* qp = Qh + ((size_t)bh * SDIM + qloc + c) * HDIM;
  bf16x8 qa0 = *(const bf16x8*)(qp + g * 8);
  bf16x8 qa1 = *(const bf16x8*)(qp + 32 + g * 8);

  const u16* kbase = Kh + (size_t)bh * SDIM * HDIM;
  const u16* vbase = Vt + (size_t)bh * HDIM * SDIM;
  const u16* wbase = wm + (size_t)b * SDIM * SDIM;

  float l_run[4] = {0.f, 0.f, 0.f, 0.f};
  f32x4 acc_o[4] = {};

  const int xr = (c & 8) << 2;               // read-side XOR (bit5) for row=c

  for (int kt = 0; kt < 16; ++kt) {
    const int k0 = kt * 64;

    // weights (independent, issue first)
    ushort4 w4[4];
    #pragma unroll
    for (int st = 0; st < 4; ++st)
      w4[st] = *(const ushort4*)(wbase + (size_t)(k0 + st * 16 + c) * SDIM + qloc + g * 4);

    // K fragments + QK^T
    f32x4 sc[4];
    #pragma unroll
    for (int st = 0; st < 4; ++st) {
      const u16* kp = kbase + (size_t)(k0 + st * 16 + c) * HDIM;
      bf16x8 kb0 = *(const bf16x8*)(kp + g * 8);
      bf16x8 kb1 = *(const bf16x8*)(kp + 32 + g * 8);
      f32x4 z = {};
      z = __builtin_amdgcn_mfma_f32_16x16x32_bf16(qa0, kb0, z, 0, 0, 0);
      z = __builtin_amdgcn_mfma_f32_16x16x32_bf16(qa1, kb1, z, 0, 0, 0);
      sc[st] = z;
    }

    // V fragments (independent - issue before softmax to hide latency)
    bf16x8 vb0[4], vb1[4];
    #pragma unroll
    for (int dt = 0; dt < 4; ++dt) {
      const u16* vp = vbase + (size_t)(dt * 16 + c) * SDIM + k0;
      vb0[dt] = *(const bf16x8*)(vp + g * 8);
      vb1[dt] = *(const bf16x8*)(vp + 32 + g * 8);
    }

    // p = w * exp(s); masked -> w==0 -> p==0 exactly. No max-subtraction.
    #pragma unroll
    for (int st = 0; st < 4; ++st) {
      #pragma unroll
      for (int r = 0; r < 4; ++r) {
        float w = bf2f(((const u16*)&w4[st])[r]);
        float p = w * __expf(sc[st][r]);
        u16 pb = f2bf(p);
        l_run[r] += bf2f(pb);
        int row = g * 4 + r;
        int colb = (st * 16 + c) * 2;
        *(u16*)(pw + row * 144 + (colb ^ ((row & 8) << 2))) = pb;
      }
    }

    // P fragments (same wave wrote them; compiler inserts lgkmcnt waits)
    bf16x8 pa0 = *(const bf16x8*)(pw + c * 144 + ((g * 16) ^ xr));
    bf16x8 pa1 = *(const bf16x8*)(pw + c * 144 + ((64 + g * 16) ^ xr));

    // PV
    #pragma unroll
    for (int dt = 0; dt < 4; ++dt) {
      acc_o[dt] = __builtin_amdgcn_mfma_f32_16x16x32_bf16(pa0, vb0[dt], acc_o[dt], 0, 0, 0);
      acc_o[dt] = __builtin_amdgcn_mfma_f32_16x16x32_bf16(pa1, vb1[dt], acc_o[dt], 0, 0, 0);
    }
  }

  // row-sum reduce across the 16-lane c-group (only once, at the end)
  #pragma unroll
  for (int r = 0; r < 4; ++r) {
    #pragma unroll
    for (int o = 1; o < 16; o <<= 1) l_run[r] += __shfl_xor(l_run[r], o);
  }
  float inv[4];
  #pragma unroll
  for (int r = 0; r < 4; ++r) inv[r] = 1.0f / l_run[r];

  #pragma unroll
  for (int dt = 0; dt < 4; ++dt)
    #pragma unroll
    for (int r = 0; r < 4; ++r) {
      int row = b * SDIM + qloc + g * 4 + r;
      vals[(size_t)row * EMB + h * HDIM + dt * 16 + c] = f2bf(acc_o[dt][r] * inv[r]);
    }
}

extern "C" void kernel_launch(void* const* d_in, const int* in_sizes, int n_in,
                              void* d_out, int out_size, void* d_ws, size_t ws_size,
                              hipStream_t stream) {
  const float* x     = (const float*)d_in[0];
  const int*   mask  = (const int*)d_in[1];
  const float* wts   = (const float*)d_in[2];
  const float* W_qkv = (const float*)d_in[3];
  const float* b_qkv = (const float*)d_in[4];
  const float* W_o   = (const float*)d_in[5];
  const float* b_o   = (const float*)d_in[6];
  float* out = (float*)d_out;

  char* ws = (char*)d_ws;
  u16* xb   = (u16*)(ws);                     //  8 MB x bf16 [4096][1024]
  u16* wqb  = (u16*)(ws + (8ull  << 20));     //  6 MB W_qkv bf16
  u16* wob  = (u16*)(ws + (14ull << 20));     //  2 MB W_o bf16
  u16* Qh   = (u16*)(ws + (16ull << 20));     //  8 MB [bh][s][64]
  u16* Kh   = (u16*)(ws + (24ull << 20));     //  8 MB [bh][s][64]
  u16* Vt   = (u16*)(ws + (32ull << 20));     //  8 MB [bh][64][s]
  u16* valb = (u16*)(ws + (40ull << 20));     //  8 MB attn out bf16
  u16* wmb  = (u16*)(ws);                     //  8 MB wm bf16, overlaps xb (dead after gemm1)

  cvt_bf16_kernel<<<2048, 256, 0, stream>>>(x,     xb,  (BATCH * SDIM * KDIM) / 8);
  cvt_bf16_kernel<<<1536, 256, 0, stream>>>(W_qkv, wqb, (N_QKV * KDIM) / 8);
  cvt_bf16_kernel<<<512,  256, 0, stream>>>(W_o,   wob, (EMB * EMB) / 8);

  dim3 g1(32, 24);
  gemm_qkv<<<g1, 256, 0, stream>>>(xb, wqb, b_qkv, Qh, Kh, Vt);

  dim3 gw(16, 16, 4);
  wm_kernel<<<gw, 256, 0, stream>>>(mask, wts, wmb);

  attn_kernel<<<1024, 256, 0, stream>>>(Qh, Kh, Vt, wmb, valb);

  dim3 g3(32, 8);
  gemm_bt<<<g3, 256, 0, stream>>>(valb, wob, b_o, out, BATCH * SDIM, EMB, KDIM);
}

// Round 3
// 151.342 us; speedup vs baseline: 1.6437x; 1.6437x over previous
//
#include <hip/hip_runtime.h>
#include <hip/hip_bf16.h>
#include <stdint.h>

#define SDIM 1024
#define BATCH 4
#define NH 16
#define HDIM 64
#define KDIM 1024
#define N_QKV 3072
#define EMB 1024

typedef uint16_t u16;
typedef __attribute__((ext_vector_type(4))) float f32x4;
typedef __attribute__((ext_vector_type(8))) short bf16x8;
typedef __attribute__((ext_vector_type(8))) unsigned short u16x8;

__device__ __forceinline__ u16 f2bf(float f) {
  union { float f; uint32_t u; } x; x.f = f;
  uint32_t r = x.u + 0x7FFFu + ((x.u >> 16) & 1u);
  return (u16)(r >> 16);
}

__device__ __forceinline__ float bf2f(u16 b) {
  union { uint32_t u; float f; } x; x.u = ((uint32_t)b) << 16;
  return x.f;
}

__device__ __forceinline__ void gload_lds16(const u16* g, u16* l) {
  __builtin_amdgcn_global_load_lds(
      (const __attribute__((address_space(1))) unsigned int*)g,
      (__attribute__((address_space(3))) unsigned int*)l, 16, 0, 0);
}

// ---------------- merged f32 -> bf16 conversion ----------------
#define N8_X  524288   // 4096*1024/8
#define N8_WQ 393216   // 3072*1024/8
#define N8_WO 131072   // 1024*1024/8
__global__ void cvt3_kernel(const float* __restrict__ a, const float* __restrict__ b,
                            const float* __restrict__ c,
                            u16* __restrict__ oa, u16* __restrict__ ob, u16* __restrict__ oc) {
  const int total = N8_X + N8_WQ + N8_WO;
  int stride = gridDim.x * blockDim.x;
  for (int i = blockIdx.x * blockDim.x + threadIdx.x; i < total; i += stride) {
    const float* s; u16* d; int j;
    if (i < N8_X)            { s = a; d = oa; j = i; }
    else if (i < N8_X + N8_WQ){ s = b; d = ob; j = i - N8_X; }
    else                     { s = c; d = oc; j = i - N8_X - N8_WQ; }
    const float4* s4 = (const float4*)s + (size_t)j * 2;
    float4 u = s4[0], v = s4[1];
    u16x8 o;
    o[0] = f2bf(u.x); o[1] = f2bf(u.y); o[2] = f2bf(u.z); o[3] = f2bf(u.w);
    o[4] = f2bf(v.x); o[5] = f2bf(v.y); o[6] = f2bf(v.z); o[7] = f2bf(v.w);
    ((u16x8*)d)[j] = o;
  }
}

// ---------------- wm3: fragment-ordered masked weights ----------------
// wm3[b][qt][wid][kt][st][ (g*16+c)*4 + r ] = mask[b][q][k] ? wts[b][k][q] : 0  (bf16)
//   q = qt*64 + wid*16 + g*4 + r,  k = kt*64 + st*16 + c
__global__ __launch_bounds__(256) void wm3_kernel(
    const int* __restrict__ mask, const float* __restrict__ wts, u16* __restrict__ wm3)
{
  const int kt = blockIdx.x, qt = blockIdx.y, b = blockIdx.z;
  const int q0 = qt * 64, k0 = kt * 64;
  const size_t SS = (size_t)SDIM * SDIM;
  __shared__ int   mt[64][68];   // [q][k]
  __shared__ float wt[64][68];   // [k][q]
  const int t = threadIdx.x;

  #pragma unroll
  for (int j = 0; j < 4; ++j) {
    int idx = j * 256 + t;              // 1024 16B-chunks
    int row = idx >> 4, c4 = idx & 15;
    int4 m4 = *(const int4*)(mask + (size_t)b * SS + (size_t)(q0 + row) * SDIM + k0 + c4 * 4);
    mt[row][c4 * 4 + 0] = m4.x; mt[row][c4 * 4 + 1] = m4.y;
    mt[row][c4 * 4 + 2] = m4.z; mt[row][c4 * 4 + 3] = m4.w;
    float4 w4 = *(const float4*)(wts + (size_t)b * SS + (size_t)(k0 + row) * SDIM + q0 + c4 * 4);
    wt[row][c4 * 4 + 0] = w4.x; wt[row][c4 * 4 + 1] = w4.y;
    wt[row][c4 * 4 + 2] = w4.z; wt[row][c4 * 4 + 3] = w4.w;
  }
  __syncthreads();

  const int st = t >> 6, lane = t & 63, g = lane >> 4, c = lane & 15;
  const int kl = st * 16 + c;
  #pragma unroll
  for (int wid = 0; wid < 4; ++wid) {
    ushort4 o;
    u16* oe = (u16*)&o;
    #pragma unroll
    for (int r = 0; r < 4; ++r) {
      int ql = wid * 16 + g * 4 + r;
      oe[r] = mt[ql][kl] ? f2bf(wt[kl][ql]) : (u16)0;
    }
    size_t off = (((((size_t)b * 16 + qt) * 4 + wid) * 16 + kt) * 4 + st) * 256 + (g * 16 + c) * 4;
    *(ushort4*)(wm3 + off) = o;
  }
}

// ---------------- GEMM1: qkv projection, routed epilogue ----------------
__global__ __launch_bounds__(256) void gemm_qkv(
    const u16* __restrict__ A, const u16* __restrict__ Bm,
    const float* __restrict__ bias,
    u16* __restrict__ Qh, u16* __restrict__ Kh, u16* __restrict__ Vt)
{
  __shared__ u16 As[128 * 64];
  __shared__ u16 Bs[128 * 64];
  const int tid = threadIdx.x;
  const int wid = tid >> 6, lane = tid & 63;
  const int g = lane >> 4, c = lane & 15;
  const int wrow = (wid >> 1) * 64, wcol = (wid & 1) * 64;
  const int brow = blockIdx.x * 128, bcol = blockIdx.y * 128;
  const int K = KDIM;

  f32x4 acc[4][4] = {};

  for (int kt = 0; kt < K / 64; ++kt) {
    #pragma unroll
    for (int j = 0; j < 4; ++j) {
      int ci = j * 256 + tid;
      int r = ci >> 3, c8 = ci & 7;
      gload_lds16(A  + (size_t)(brow + r) * K + kt * 64 + c8 * 8,
                  As + (size_t)(j * 256 + wid * 64) * 8);
      gload_lds16(Bm + (size_t)(bcol + r) * K + kt * 64 + c8 * 8,
                  Bs + (size_t)(j * 256 + wid * 64) * 8);
    }
    __syncthreads();

    bf16x8 af[2][4], bfr[2][4];
    #pragma unroll
    for (int kk = 0; kk < 2; ++kk)
      #pragma unroll
      for (int i = 0; i < 4; ++i) {
        af[kk][i]  = *(const bf16x8*)&As[(wrow + i * 16 + c) * 64 + kk * 32 + g * 8];
        bfr[kk][i] = *(const bf16x8*)&Bs[(wcol + i * 16 + c) * 64 + kk * 32 + g * 8];
      }
    #pragma unroll
    for (int kk = 0; kk < 2; ++kk)
      #pragma unroll
      for (int mi = 0; mi < 4; ++mi)
        #pragma unroll
        for (int ni = 0; ni < 4; ++ni)
          acc[mi][ni] = __builtin_amdgcn_mfma_f32_16x16x32_bf16(
              af[kk][mi], bfr[kk][ni], acc[mi][ni], 0, 0, 0);
    __syncthreads();
  }

  #pragma unroll
  for (int mi = 0; mi < 4; ++mi) {
    #pragma unroll
    for (int ni = 0; ni < 4; ++ni) {
      int col = bcol + wcol + ni * 16 + c;
      float bv = bias[col];
      int h = col / 192;
      int rem = col - h * 192;
      int sec = rem >> 6, d = rem & 63;
      #pragma unroll
      for (int r = 0; r < 4; ++r) {
        int row = brow + wrow + mi * 16 + g * 4 + r;
        int b = row >> 10, sl = row & 1023;
        float v = acc[mi][ni][r] + bv;
        if (sec == 0)
          Qh[((size_t)(b * NH + h) * SDIM + sl) * HDIM + d] = f2bf(v * 0.125f);
        else if (sec == 1)
          Kh[((size_t)(b * NH + h) * SDIM + sl) * HDIM + d] = f2bf(v);
        else
          Vt[((size_t)(b * NH + h) * HDIM + d) * SDIM + sl] = f2bf(v);
      }
    }
  }
}

// ---------------- GEMM2 ----------------
__global__ __launch_bounds__(256) void gemm_bt(
    const u16* __restrict__ A, const u16* __restrict__ Bm,
    const float* __restrict__ bias, float* __restrict__ C,
    int M, int N, int K)
{
  __shared__ u16 As[128 * 64];
  __shared__ u16 Bs[128 * 64];
  const int tid = threadIdx.x;
  const int wid = tid >> 6, lane = tid & 63;
  const int g = lane >> 4, c = lane & 15;
  const int wrow = (wid >> 1) * 64, wcol = (wid & 1) * 64;
  const int brow = blockIdx.x * 128, bcol = blockIdx.y * 128;

  f32x4 acc[4][4] = {};

  for (int kt = 0; kt < K / 64; ++kt) {
    #pragma unroll
    for (int j = 0; j < 4; ++j) {
      int ci = j * 256 + tid;
      int r = ci >> 3, c8 = ci & 7;
      gload_lds16(A  + (size_t)(brow + r) * K + kt * 64 + c8 * 8,
                  As + (size_t)(j * 256 + wid * 64) * 8);
      gload_lds16(Bm + (size_t)(bcol + r) * K + kt * 64 + c8 * 8,
                  Bs + (size_t)(j * 256 + wid * 64) * 8);
    }
    __syncthreads();

    bf16x8 af[2][4], bfr[2][4];
    #pragma unroll
    for (int kk = 0; kk < 2; ++kk)
      #pragma unroll
      for (int i = 0; i < 4; ++i) {
        af[kk][i]  = *(const bf16x8*)&As[(wrow + i * 16 + c) * 64 + kk * 32 + g * 8];
        bfr[kk][i] = *(const bf16x8*)&Bs[(wcol + i * 16 + c) * 64 + kk * 32 + g * 8];
      }
    #pragma unroll
    for (int kk = 0; kk < 2; ++kk)
      #pragma unroll
      for (int mi = 0; mi < 4; ++mi)
        #pragma unroll
        for (int ni = 0; ni < 4; ++ni)
          acc[mi][ni] = __builtin_amdgcn_mfma_f32_16x16x32_bf16(
              af[kk][mi], bfr[kk][ni], acc[mi][ni], 0, 0, 0);
    __syncthreads();
  }

  #pragma unroll
  for (int mi = 0; mi < 4; ++mi)
    #pragma unroll
    for (int ni = 0; ni < 4; ++ni) {
      int col = bcol + wcol + ni * 16 + c;
      float bv = bias[col];
      #pragma unroll
      for (int r = 0; r < 4; ++r) {
        int row = brow + wrow + mi * 16 + g * 4 + r;
        C[(size_t)row * N + col] = acc[mi][ni][r] + bv;
      }
    }
}

// ---------------- attention: LDS-staged, double-buffered, coalesced ----------------
// Qh/Kh [bh][s][64] bf16 (Q pre-scaled 1/8), Vt [bh][64][s] bf16,
// wm3 fragment-ordered bf16, vals [b*s][1024] bf16
__global__ __launch_bounds__(256, 3) void attn_kernel(
    const u16* __restrict__ Qh, const u16* __restrict__ Kh, const u16* __restrict__ Vt,
    const u16* __restrict__ wm3, u16* __restrict__ vals)
{
  int bid = blockIdx.x;
  int swz = (bid & 7) * 128 + (bid >> 3);   // 8 bh per XCD
  const int qt = swz & 15, bh = swz >> 4;
  const int h = bh & 15, b = bh >> 4;

  const int tid = threadIdx.x;
  const int wid = tid >> 6, lane = tid & 63;
  const int g = lane >> 4, c = lane & 15;
  const int qloc = qt * 64 + wid * 16;

  __shared__ u16 Kb[2][4096];     // [64 k][8 chunk-swz][8 el]
  __shared__ u16 Vb[2][4096];     // [64 d][8 chunk-swz][8 el]
  __shared__ u16 Plds[4][16 * 72];
  char* pw = (char*)&Plds[wid][0];

  const u16* qp = Qh + ((size_t)bh * SDIM + qloc + c) * HDIM;
  bf16x8 qa0 = *(const bf16x8*)(qp + g * 8);
  bf16x8 qa1 = *(const bf16x8*)(qp + 32 + g * 8);

  const u16* kbase = Kh + (size_t)bh * SDIM * HDIM;
  const u16* vbase = Vt + (size_t)bh * HDIM * SDIM;
  const u16* wbase = wm3 + ((((size_t)(b * 16 + qt) * 4 + wid) * 16) * 4) * 256 + (g * 16 + c) * 4;

  float l_run[4] = {0.f, 0.f, 0.f, 0.f};
  f32x4 acc_o[4] = {};
  const int xr = (c & 8) << 2;
  const int cx = c & 7;

  // stage tile kt into buffer buf (source pre-swizzled: LDS[row][ch] = glob[row][ch^(row&7)])
  auto stage = [&](int buf, int kt) {
    const int k0 = kt * 64;
    #pragma unroll
    for (int j = 0; j < 2; ++j) {
      int i = j * 256 + tid;
      int row = i >> 3, sch = (i & 7) ^ (row & 7);
      gload_lds16(kbase + (size_t)(k0 + row) * HDIM + sch * 8,
                  &Kb[buf][(size_t)(j * 256 + wid * 64) * 8]);
      gload_lds16(vbase + (size_t)row * SDIM + k0 + sch * 8,
                  &Vb[buf][(size_t)(j * 256 + wid * 64) * 8]);
    }
  };

  stage(0, 0);
  __syncthreads();
  int cur = 0;

  for (int kt = 0; kt < 16; ++kt) {
    if (kt < 15) stage(cur ^ 1, kt + 1);

    // weights: 4 coalesced 8B loads (fragment-ordered)
    ushort4 w4[4];
    #pragma unroll
    for (int st = 0; st < 4; ++st)
      w4[st] = *(const ushort4*)(wbase + (size_t)(kt * 4 + st) * 256);

    const char* kb = (const char*)&Kb[cur][0];
    const char* vb = (const char*)&Vb[cur][0];

    // QK^T from LDS (swizzled reads)
    f32x4 sc[4];
    #pragma unroll
    for (int st = 0; st < 4; ++st) {
      int ro = (st * 16 + c) * 128;
      bf16x8 kb0 = *(const bf16x8*)(kb + ro + ((g ^ cx) << 4));
      bf16x8 kb1 = *(const bf16x8*)(kb + ro + (((4 + g) ^ cx) << 4));
      f32x4 z = {};
      z = __builtin_amdgcn_mfma_f32_16x16x32_bf16(qa0, kb0, z, 0, 0, 0);
      z = __builtin_amdgcn_mfma_f32_16x16x32_bf16(qa1, kb1, z, 0, 0, 0);
      sc[st] = z;
    }

    // V^T fragments from LDS
    bf16x8 vb0[4], vb1[4];
    #pragma unroll
    for (int dt = 0; dt < 4; ++dt) {
      int ro = (dt * 16 + c) * 128;
      vb0[dt] = *(const bf16x8*)(vb + ro + ((g ^ cx) << 4));
      vb1[dt] = *(const bf16x8*)(vb + ro + (((4 + g) ^ cx) << 4));
    }

    // p = w * exp(s); masked -> w==0 -> p==0 exactly
    #pragma unroll
    for (int st = 0; st < 4; ++st) {
      #pragma unroll
      for (int r = 0; r < 4; ++r) {
        float w = bf2f(((const u16*)&w4[st])[r]);
        float p = w * __expf(sc[st][r]);
        u16 pb = f2bf(p);
        l_run[r] += bf2f(pb);
        int row = g * 4 + r;
        int colb = (st * 16 + c) * 2;
        *(u16*)(pw + row * 144 + (colb ^ ((row & 8) << 2))) = pb;
      }
    }

    // P fragments (same-wave LDS round-trip)
    bf16x8 pa0 = *(const bf16x8*)(pw + c * 144 + ((g * 16) ^ xr));
    bf16x8 pa1 = *(const bf16x8*)(pw + c * 144 + ((64 + g * 16) ^ xr));

    #pragma unroll
    for (int dt = 0; dt < 4; ++dt) {
      acc_o[dt] = __builtin_amdgcn_mfma_f32_16x16x32_bf16(pa0, vb0[dt], acc_o[dt], 0, 0, 0);
      acc_o[dt] = __builtin_amdgcn_mfma_f32_16x16x32_bf16(pa1, vb1[dt], acc_o[dt], 0, 0, 0);
    }

    __syncthreads();   // drains my stage(kt+1) vmcnt; all waves done reading cur
    cur ^= 1;
  }

  #pragma unroll
  for (int r = 0; r < 4; ++r) {
    #pragma unroll
    for (int o = 1; o < 16; o <<= 1) l_run[r] += __shfl_xor(l_run[r], o);
  }
  float inv[4];
  #pragma unroll
  for (int r = 0; r < 4; ++r) inv[r] = 1.0f / l_run[r];

  #pragma unroll
  for (int dt = 0; dt < 4; ++dt)
    #pragma unroll
    for (int r = 0; r < 4; ++r) {
      int row = b * SDIM + qloc + g * 4 + r;
      vals[(size_t)row * EMB + h * HDIM + dt * 16 + c] = f2bf(acc_o[dt][r] * inv[r]);
    }
}

extern "C" void kernel_launch(void* const* d_in, const int* in_sizes, int n_in,
                              void* d_out, int out_size, void* d_ws, size_t ws_size,
                              hipStream_t stream) {
  const float* x     = (const float*)d_in[0];
  const int*   mask  = (const int*)d_in[1];
  const float* wts   = (const float*)d_in[2];
  const float* W_qkv = (const float*)d_in[3];
  const float* b_qkv = (const float*)d_in[4];
  const float* W_o   = (const float*)d_in[5];
  const float* b_o   = (const float*)d_in[6];
  float* out = (float*)d_out;

  char* ws = (char*)d_ws;
  u16* xb   = (u16*)(ws);                     //  8 MB x bf16
  u16* wqb  = (u16*)(ws + (8ull  << 20));     //  6 MB W_qkv bf16
  u16* wob  = (u16*)(ws + (14ull << 20));     //  2 MB W_o bf16
  u16* Qh   = (u16*)(ws + (16ull << 20));     //  8 MB [bh][s][64]
  u16* Kh   = (u16*)(ws + (24ull << 20));     //  8 MB [bh][s][64]
  u16* Vt   = (u16*)(ws + (32ull << 20));     //  8 MB [bh][64][s]
  u16* valb = (u16*)(ws + (40ull << 20));     //  8 MB attn out bf16
  u16* wm3b = (u16*)(ws);                     //  8 MB, overlaps xb (dead after gemm1)

  cvt3_kernel<<<2048, 256, 0, stream>>>(x, W_qkv, W_o, xb, wqb, wob);

  dim3 g1(32, 24);
  gemm_qkv<<<g1, 256, 0, stream>>>(xb, wqb, b_qkv, Qh, Kh, Vt);

  dim3 gw(16, 16, 4);   // kt, qt, b
  wm3_kernel<<<gw, 256, 0, stream>>>(mask, wts, wm3b);

  attn_kernel<<<1024, 256, 0, stream>>>(Qh, Kh, Vt, wm3b, valb);

  dim3 g3(32, 8);
  gemm_bt<<<g3, 256, 0, stream>>>(valb, wob, b_o, out, BATCH * SDIM, EMB, KDIM);
}

// Round 4
// 140.929 us; speedup vs baseline: 1.7652x; 1.0739x over previous
//
#include <hip/hip_runtime.h>
#include <hip/hip_bf16.h>
#include <stdint.h>

#define SDIM 1024
#define BATCH 4
#define NH 16
#define HDIM 64
#define KDIM 1024
#define N_QKV 3072
#define EMB 1024

typedef uint16_t u16;
typedef __attribute__((ext_vector_type(4))) float f32x4;
typedef __attribute__((ext_vector_type(8))) short bf16x8;
typedef __attribute__((ext_vector_type(8))) unsigned short u16x8;

__device__ __forceinline__ u16 f2bf(float f) {
  union { float f; uint32_t u; } x; x.f = f;
  uint32_t r = x.u + 0x7FFFu + ((x.u >> 16) & 1u);
  return (u16)(r >> 16);
}

__device__ __forceinline__ float bf2f(u16 b) {
  union { uint32_t u; float f; } x; x.u = ((uint32_t)b) << 16;
  return x.f;
}

__device__ __forceinline__ void gload_lds16(const u16* g, u16* l) {
  __builtin_amdgcn_global_load_lds(
      (const __attribute__((address_space(1))) unsigned int*)g,
      (__attribute__((address_space(3))) unsigned int*)l, 16, 0, 0);
}

// ---------------- merged f32 -> bf16 conversion ----------------
#define N8_X  524288
#define N8_WQ 393216
#define N8_WO 131072
__global__ void cvt3_kernel(const float* __restrict__ a, const float* __restrict__ b,
                            const float* __restrict__ c,
                            u16* __restrict__ oa, u16* __restrict__ ob, u16* __restrict__ oc) {
  const int total = N8_X + N8_WQ + N8_WO;
  int stride = gridDim.x * blockDim.x;
  for (int i = blockIdx.x * blockDim.x + threadIdx.x; i < total; i += stride) {
    const float* s; u16* d; int j;
    if (i < N8_X)            { s = a; d = oa; j = i; }
    else if (i < N8_X + N8_WQ){ s = b; d = ob; j = i - N8_X; }
    else                     { s = c; d = oc; j = i - N8_X - N8_WQ; }
    const float4* s4 = (const float4*)s + (size_t)j * 2;
    float4 u = s4[0], v = s4[1];
    u16x8 o;
    o[0] = f2bf(u.x); o[1] = f2bf(u.y); o[2] = f2bf(u.z); o[3] = f2bf(u.w);
    o[4] = f2bf(v.x); o[5] = f2bf(v.y); o[6] = f2bf(v.z); o[7] = f2bf(v.w);
    ((u16x8*)d)[j] = o;
  }
}

// ---------------- merged GEMM1(qkv, routed epilogue) + wm3 prep ----------------
// grid: 1792 blocks, groups of 7 = 3 gemm + 4 wm3 (interleaved co-residency)
__global__ __launch_bounds__(256) void gemm_qkv_wm3(
    const u16* __restrict__ A, const u16* __restrict__ Bm,
    const float* __restrict__ bias,
    u16* __restrict__ Qh, u16* __restrict__ Kh, u16* __restrict__ Vt,
    const int* __restrict__ mask, const float* __restrict__ wts, u16* __restrict__ wm3)
{
  __shared__ char smem[36864];
  const int grp = blockIdx.x / 7, r7 = blockIdx.x % 7;
  const int tid = threadIdx.x;

  if (r7 < 3) {
    // ---------- GEMM part ----------
    const int gid = grp * 3 + r7;           // 0..767, x-fastest
    const int brow = (gid & 31) * 128, bcol = (gid >> 5) * 128;
    u16* As = (u16*)smem;
    u16* Bs = (u16*)(smem + 16384);
    const int wid = tid >> 6, lane = tid & 63;
    const int g = lane >> 4, c = lane & 15, cx = c & 7;
    const int wrow = (wid >> 1) * 64, wcol = (wid & 1) * 64;

    const u16* asrc[4]; const u16* bsrc[4]; u16* adst[4]; u16* bdst[4];
    #pragma unroll
    for (int j = 0; j < 4; ++j) {
      int ci = j * 256 + tid;
      int row = ci >> 3, sch = (ci & 7) ^ (row & 7);   // pre-swizzled source chunk
      asrc[j] = A  + (size_t)(brow + row) * KDIM + sch * 8;
      bsrc[j] = Bm + (size_t)(bcol + row) * KDIM + sch * 8;
      adst[j] = As + (j * 256 + wid * 64) * 8;
      bdst[j] = Bs + (j * 256 + wid * 64) * 8;
    }

    f32x4 acc[4][4] = {};
    const char* Asc = (const char*)As;
    const char* Bsc = (const char*)Bs;

    for (int kt = 0; kt < 16; ++kt) {
      #pragma unroll
      for (int j = 0; j < 4; ++j) {
        gload_lds16(asrc[j] + kt * 64, adst[j]);
        gload_lds16(bsrc[j] + kt * 64, bdst[j]);
      }
      __syncthreads();

      bf16x8 af[2][4], bfr[2][4];
      #pragma unroll
      for (int kk = 0; kk < 2; ++kk)
        #pragma unroll
        for (int i = 0; i < 4; ++i) {
          int cha = ((kk << 2) + g) ^ cx;
          af[kk][i]  = *(const bf16x8*)(Asc + ((wrow + i * 16 + c) << 7) + (cha << 4));
          bfr[kk][i] = *(const bf16x8*)(Bsc + ((wcol + i * 16 + c) << 7) + (cha << 4));
        }
      #pragma unroll
      for (int kk = 0; kk < 2; ++kk)
        #pragma unroll
        for (int mi = 0; mi < 4; ++mi)
          #pragma unroll
          for (int ni = 0; ni < 4; ++ni)
            acc[mi][ni] = __builtin_amdgcn_mfma_f32_16x16x32_bf16(
                af[kk][mi], bfr[kk][ni], acc[mi][ni], 0, 0, 0);
      __syncthreads();
    }

    #pragma unroll
    for (int mi = 0; mi < 4; ++mi) {
      #pragma unroll
      for (int ni = 0; ni < 4; ++ni) {
        int col = bcol + wcol + ni * 16 + c;
        float bv = bias[col];
        int h = col / 192;
        int rem = col - h * 192;
        int sec = rem >> 6, d = rem & 63;
        #pragma unroll
        for (int r = 0; r < 4; ++r) {
          int row = brow + wrow + mi * 16 + g * 4 + r;
          int b = row >> 10, sl = row & 1023;
          float v = acc[mi][ni][r] + bv;
          if (sec == 0)
            Qh[((size_t)(b * NH + h) * SDIM + sl) * HDIM + d] = f2bf(v * 0.125f);
          else if (sec == 1)
            Kh[((size_t)(b * NH + h) * SDIM + sl) * HDIM + d] = f2bf(v);
          else
            Vt[((size_t)(b * NH + h) * HDIM + d) * SDIM + sl] = f2bf(v);
        }
      }
    }
  } else {
    // ---------- wm3 part ----------
    const int wmid = grp * 4 + (r7 - 3);    // 0..1023
    const int kt = wmid & 15, qt = (wmid >> 4) & 15, b = wmid >> 8;
    const int q0 = qt * 64, k0 = kt * 64;
    const size_t SS = (size_t)SDIM * SDIM;
    int   (*mt)[68] = (int(*)[68])smem;            // [q][k]
    float (*wt)[68] = (float(*)[68])(smem + 17408); // [k][q]

    #pragma unroll
    for (int j = 0; j < 4; ++j) {
      int idx = j * 256 + tid;
      int row = idx >> 4, c4 = idx & 15;
      int4 m4 = *(const int4*)(mask + (size_t)b * SS + (size_t)(q0 + row) * SDIM + k0 + c4 * 4);
      mt[row][c4 * 4 + 0] = m4.x; mt[row][c4 * 4 + 1] = m4.y;
      mt[row][c4 * 4 + 2] = m4.z; mt[row][c4 * 4 + 3] = m4.w;
      float4 w4 = *(const float4*)(wts + (size_t)b * SS + (size_t)(k0 + row) * SDIM + q0 + c4 * 4);
      wt[row][c4 * 4 + 0] = w4.x; wt[row][c4 * 4 + 1] = w4.y;
      wt[row][c4 * 4 + 2] = w4.z; wt[row][c4 * 4 + 3] = w4.w;
    }
    __syncthreads();

    const int st = tid >> 6, lane = tid & 63, g = lane >> 4, c = lane & 15;
    const int kl = st * 16 + c;
    #pragma unroll
    for (int wid = 0; wid < 4; ++wid) {
      ushort4 o;
      u16* oe = (u16*)&o;
      #pragma unroll
      for (int r = 0; r < 4; ++r) {
        int ql = wid * 16 + g * 4 + r;
        oe[r] = mt[ql][kl] ? f2bf(wt[kl][ql]) : (u16)0;
      }
      size_t off = (((((size_t)b * 16 + qt) * 4 + wid) * 16 + kt) * 4 + st) * 256 + (g * 16 + c) * 4;
      *(ushort4*)(wm3 + off) = o;
    }
  }
}

// ---------------- GEMM2 (swizzled LDS) ----------------
__global__ __launch_bounds__(256) void gemm_bt(
    const u16* __restrict__ A, const u16* __restrict__ Bm,
    const float* __restrict__ bias, float* __restrict__ C,
    int M, int N, int K)
{
  __shared__ u16 As[128 * 64];
  __shared__ u16 Bs[128 * 64];
  const int tid = threadIdx.x;
  const int wid = tid >> 6, lane = tid & 63;
  const int g = lane >> 4, c = lane & 15, cx = c & 7;
  const int wrow = (wid >> 1) * 64, wcol = (wid & 1) * 64;
  const int brow = blockIdx.x * 128, bcol = blockIdx.y * 128;

  const u16* asrc[4]; const u16* bsrc[4]; u16* adst[4]; u16* bdst[4];
  #pragma unroll
  for (int j = 0; j < 4; ++j) {
    int ci = j * 256 + tid;
    int row = ci >> 3, sch = (ci & 7) ^ (row & 7);
    asrc[j] = A  + (size_t)(brow + row) * K + sch * 8;
    bsrc[j] = Bm + (size_t)(bcol + row) * K + sch * 8;
    adst[j] = As + (j * 256 + wid * 64) * 8;
    bdst[j] = Bs + (j * 256 + wid * 64) * 8;
  }

  f32x4 acc[4][4] = {};
  const char* Asc = (const char*)As;
  const char* Bsc = (const char*)Bs;

  for (int kt = 0; kt < K / 64; ++kt) {
    #pragma unroll
    for (int j = 0; j < 4; ++j) {
      gload_lds16(asrc[j] + kt * 64, adst[j]);
      gload_lds16(bsrc[j] + kt * 64, bdst[j]);
    }
    __syncthreads();

    bf16x8 af[2][4], bfr[2][4];
    #pragma unroll
    for (int kk = 0; kk < 2; ++kk)
      #pragma unroll
      for (int i = 0; i < 4; ++i) {
        int cha = ((kk << 2) + g) ^ cx;
        af[kk][i]  = *(const bf16x8*)(Asc + ((wrow + i * 16 + c) << 7) + (cha << 4));
        bfr[kk][i] = *(const bf16x8*)(Bsc + ((wcol + i * 16 + c) << 7) + (cha << 4));
      }
    #pragma unroll
    for (int kk = 0; kk < 2; ++kk)
      #pragma unroll
      for (int mi = 0; mi < 4; ++mi)
        #pragma unroll
        for (int ni = 0; ni < 4; ++ni)
          acc[mi][ni] = __builtin_amdgcn_mfma_f32_16x16x32_bf16(
              af[kk][mi], bfr[kk][ni], acc[mi][ni], 0, 0, 0);
    __syncthreads();
  }

  #pragma unroll
  for (int mi = 0; mi < 4; ++mi)
    #pragma unroll
    for (int ni = 0; ni < 4; ++ni) {
      int col = bcol + wcol + ni * 16 + c;
      float bv = bias[col];
      #pragma unroll
      for (int r = 0; r < 4; ++r) {
        int row = brow + wrow + mi * 16 + g * 4 + r;
        C[(size_t)row * N + col] = acc[mi][ni][r] + bv;
      }
    }
}

// ---------------- attention: LDS-staged, double-buffered, coalesced ----------------
__global__ __launch_bounds__(256, 3) void attn_kernel(
    const u16* __restrict__ Qh, const u16* __restrict__ Kh, const u16* __restrict__ Vt,
    const u16* __restrict__ wm3, u16* __restrict__ vals)
{
  int bid = blockIdx.x;
  int swz = (bid & 7) * 128 + (bid >> 3);
  const int qt = swz & 15, bh = swz >> 4;
  const int h = bh & 15, b = bh >> 4;

  const int tid = threadIdx.x;
  const int wid = tid >> 6, lane = tid & 63;
  const int g = lane >> 4, c = lane & 15;
  const int qloc = qt * 64 + wid * 16;

  __shared__ u16 Kb[2][4096];
  __shared__ u16 Vb[2][4096];
  __shared__ u16 Plds[4][16 * 72];
  char* pw = (char*)&Plds[wid][0];

  const u16* qp = Qh + ((size_t)bh * SDIM + qloc + c) * HDIM;
  bf16x8 qa0 = *(const bf16x8*)(qp + g * 8);
  bf16x8 qa1 = *(const bf16x8*)(qp + 32 + g * 8);

  const u16* kbase = Kh + (size_t)bh * SDIM * HDIM;
  const u16* vbase = Vt + (size_t)bh * HDIM * SDIM;
  const u16* wbase = wm3 + ((((size_t)(b * 16 + qt) * 4 + wid) * 16) * 4) * 256 + (g * 16 + c) * 4;

  float l_run[4] = {0.f, 0.f, 0.f, 0.f};
  f32x4 acc_o[4] = {};
  const int xr = (c & 8) << 2;
  const int cx = c & 7;

  auto stage = [&](int buf, int kt) {
    const int k0 = kt * 64;
    #pragma unroll
    for (int j = 0; j < 2; ++j) {
      int i = j * 256 + tid;
      int row = i >> 3, sch = (i & 7) ^ (row & 7);
      gload_lds16(kbase + (size_t)(k0 + row) * HDIM + sch * 8,
                  &Kb[buf][(size_t)(j * 256 + wid * 64) * 8]);
      gload_lds16(vbase + (size_t)row * SDIM + k0 + sch * 8,
                  &Vb[buf][(size_t)(j * 256 + wid * 64) * 8]);
    }
  };

  stage(0, 0);
  __syncthreads();
  int cur = 0;

  for (int kt = 0; kt < 16; ++kt) {
    if (kt < 15) stage(cur ^ 1, kt + 1);

    ushort4 w4[4];
    #pragma unroll
    for (int st = 0; st < 4; ++st)
      w4[st] = *(const ushort4*)(wbase + (size_t)(kt * 4 + st) * 256);

    const char* kb = (const char*)&Kb[cur][0];
    const char* vb = (const char*)&Vb[cur][0];

    f32x4 sc[4];
    #pragma unroll
    for (int st = 0; st < 4; ++st) {
      int ro = (st * 16 + c) * 128;
      bf16x8 kb0 = *(const bf16x8*)(kb + ro + ((g ^ cx) << 4));
      bf16x8 kb1 = *(const bf16x8*)(kb + ro + (((4 + g) ^ cx) << 4));
      f32x4 z = {};
      z = __builtin_amdgcn_mfma_f32_16x16x32_bf16(qa0, kb0, z, 0, 0, 0);
      z = __builtin_amdgcn_mfma_f32_16x16x32_bf16(qa1, kb1, z, 0, 0, 0);
      sc[st] = z;
    }

    bf16x8 vb0[4], vb1[4];
    #pragma unroll
    for (int dt = 0; dt < 4; ++dt) {
      int ro = (dt * 16 + c) * 128;
      vb0[dt] = *(const bf16x8*)(vb + ro + ((g ^ cx) << 4));
      vb1[dt] = *(const bf16x8*)(vb + ro + (((4 + g) ^ cx) << 4));
    }

    #pragma unroll
    for (int st = 0; st < 4; ++st) {
      #pragma unroll
      for (int r = 0; r < 4; ++r) {
        float w = bf2f(((const u16*)&w4[st])[r]);
        float p = w * __expf(sc[st][r]);
        u16 pb = f2bf(p);
        l_run[r] += bf2f(pb);
        int row = g * 4 + r;
        int colb = (st * 16 + c) * 2;
        *(u16*)(pw + row * 144 + (colb ^ ((row & 8) << 2))) = pb;
      }
    }

    bf16x8 pa0 = *(const bf16x8*)(pw + c * 144 + ((g * 16) ^ xr));
    bf16x8 pa1 = *(const bf16x8*)(pw + c * 144 + ((64 + g * 16) ^ xr));

    #pragma unroll
    for (int dt = 0; dt < 4; ++dt) {
      acc_o[dt] = __builtin_amdgcn_mfma_f32_16x16x32_bf16(pa0, vb0[dt], acc_o[dt], 0, 0, 0);
      acc_o[dt] = __builtin_amdgcn_mfma_f32_16x16x32_bf16(pa1, vb1[dt], acc_o[dt], 0, 0, 0);
    }

    __syncthreads();
    cur ^= 1;
  }

  #pragma unroll
  for (int r = 0; r < 4; ++r) {
    #pragma unroll
    for (int o = 1; o < 16; o <<= 1) l_run[r] += __shfl_xor(l_run[r], o);
  }
  float inv[4];
  #pragma unroll
  for (int r = 0; r < 4; ++r) inv[r] = 1.0f / l_run[r];

  #pragma unroll
  for (int dt = 0; dt < 4; ++dt)
    #pragma unroll
    for (int r = 0; r < 4; ++r) {
      int row = b * SDIM + qloc + g * 4 + r;
      vals[(size_t)row * EMB + h * HDIM + dt * 16 + c] = f2bf(acc_o[dt][r] * inv[r]);
    }
}

extern "C" void kernel_launch(void* const* d_in, const int* in_sizes, int n_in,
                              void* d_out, int out_size, void* d_ws, size_t ws_size,
                              hipStream_t stream) {
  const float* x     = (const float*)d_in[0];
  const int*   mask  = (const int*)d_in[1];
  const float* wts   = (const float*)d_in[2];
  const float* W_qkv = (const float*)d_in[3];
  const float* b_qkv = (const float*)d_in[4];
  const float* W_o   = (const float*)d_in[5];
  const float* b_o   = (const float*)d_in[6];
  float* out = (float*)d_out;

  char* ws = (char*)d_ws;
  u16* xb   = (u16*)(ws);                     //  8 MB x bf16
  u16* wqb  = (u16*)(ws + (8ull  << 20));     //  6 MB W_qkv bf16
  u16* wob  = (u16*)(ws + (14ull << 20));     //  2 MB W_o bf16
  u16* Qh   = (u16*)(ws + (16ull << 20));     //  8 MB [bh][s][64]
  u16* Kh   = (u16*)(ws + (24ull << 20));     //  8 MB [bh][s][64]
  u16* Vt   = (u16*)(ws + (32ull << 20));     //  8 MB [bh][64][s]
  u16* valb = (u16*)(ws + (40ull << 20));     //  8 MB attn out bf16
  u16* wm3b = (u16*)d_out;                    //  8 MB scratch in d_out (overwritten by gemm_bt)

  cvt3_kernel<<<2048, 256, 0, stream>>>(x, W_qkv, W_o, xb, wqb, wob);

  gemm_qkv_wm3<<<1792, 256, 0, stream>>>(xb, wqb, b_qkv, Qh, Kh, Vt, mask, wts, wm3b);

  attn_kernel<<<1024, 256, 0, stream>>>(Qh, Kh, Vt, wm3b, valb);

  dim3 g3(32, 8);
  gemm_bt<<<g3, 256, 0, stream>>>(valb, wob, b_o, out, BATCH * SDIM, EMB, KDIM);
}

// Round 5
// 136.419 us; speedup vs baseline: 1.8235x; 1.0331x over previous
//
#include <hip/hip_runtime.h>
#include <hip/hip_bf16.h>
#include <stdint.h>

#define SDIM 1024
#define BATCH 4
#define NH 16
#define HDIM 64
#define KDIM 1024
#define N_QKV 3072
#define EMB 1024

typedef uint16_t u16;
typedef __attribute__((ext_vector_type(4))) float f32x4;
typedef __attribute__((ext_vector_type(8))) short bf16x8;
typedef __attribute__((ext_vector_type(8))) unsigned short u16x8;

__device__ __forceinline__ u16 f2bf(float f) {
  union { float f; uint32_t u; } x; x.f = f;
  uint32_t r = x.u + 0x7FFFu + ((x.u >> 16) & 1u);
  return (u16)(r >> 16);
}

__device__ __forceinline__ float bf2f(u16 b) {
  union { uint32_t u; float f; } x; x.u = ((uint32_t)b) << 16;
  return x.f;
}

__device__ __forceinline__ void gload_lds16(const u16* g, u16* l) {
  __builtin_amdgcn_global_load_lds(
      (const __attribute__((address_space(1))) unsigned int*)g,
      (__attribute__((address_space(3))) unsigned int*)l, 16, 0, 0);
}

// ---------------- merged f32 -> bf16 conversion ----------------
#define N8_X  524288
#define N8_WQ 393216
#define N8_WO 131072
__global__ void cvt3_kernel(const float* __restrict__ a, const float* __restrict__ b,
                            const float* __restrict__ c,
                            u16* __restrict__ oa, u16* __restrict__ ob, u16* __restrict__ oc) {
  const int total = N8_X + N8_WQ + N8_WO;
  int stride = gridDim.x * blockDim.x;
  for (int i = blockIdx.x * blockDim.x + threadIdx.x; i < total; i += stride) {
    const float* s; u16* d; int j;
    if (i < N8_X)            { s = a; d = oa; j = i; }
    else if (i < N8_X + N8_WQ){ s = b; d = ob; j = i - N8_X; }
    else                     { s = c; d = oc; j = i - N8_X - N8_WQ; }
    const float4* s4 = (const float4*)s + (size_t)j * 2;
    float4 u = s4[0], v = s4[1];
    u16x8 o;
    o[0] = f2bf(u.x); o[1] = f2bf(u.y); o[2] = f2bf(u.z); o[3] = f2bf(u.w);
    o[4] = f2bf(v.x); o[5] = f2bf(v.y); o[6] = f2bf(v.z); o[7] = f2bf(v.w);
    ((u16x8*)d)[j] = o;
  }
}

// ---------------- GEMM1 (ring-3 counted-vmcnt) + wm3, heterogeneous grid ----------------
// GEMM: BM=256 BN=128 BK=64, 512 thr (8 waves, 4M x 2N), 3 LDS tile slots.
// Slot layout: A 256x64 bf16 (32768 B) then B 128x64 bf16 (16384 B) = 49152 B/slot.
// grid: 896 blocks of 512; per 7-group: 3 gemm (384 total) + 4 wm3 (512 total).
__global__ __launch_bounds__(512, 2) void gemm_qkv_wm3(
    const u16* __restrict__ A, const u16* __restrict__ Bm,
    const float* __restrict__ bias,
    u16* __restrict__ Qh, u16* __restrict__ Kh, u16* __restrict__ Vt,
    const int* __restrict__ mask, const float* __restrict__ wts, u16* __restrict__ wm3)
{
  __shared__ char smem[147456];
  const int grp = blockIdx.x / 7, r7 = blockIdx.x % 7;
  const int tid = threadIdx.x;

  if (r7 < 3) {
    // ---------- GEMM part ----------
    const int gid = grp * 3 + r7;                 // 0..383
    const int brow = (gid & 15) * 256, bcol = (gid >> 4) * 128;
    const int wid = tid >> 6, lane = tid & 63;
    const int g = lane >> 4, c = lane & 15, cx = c & 7;
    const int wr = wid >> 1, wc = wid & 1;        // 4 M-groups x 2 N-groups

    // per-thread staging sources (row/chunk fixed; add kt*64 per tile)
    const u16* asrc[4]; u16* adst[4];
    const u16* bsrc[2]; u16* bdst[2];
    #pragma unroll
    for (int j = 0; j < 4; ++j) {
      int i = j * 512 + tid;
      int row = i >> 3, sch = (i & 7) ^ (row & 7);
      asrc[j] = A + (size_t)(brow + row) * KDIM + sch * 8;
      adst[j] = (u16*)(smem + (j * 512 + wid * 64) * 16);
    }
    #pragma unroll
    for (int j = 0; j < 2; ++j) {
      int i = j * 512 + tid;
      int row = i >> 3, sch = (i & 7) ^ (row & 7);
      bsrc[j] = Bm + (size_t)(bcol + row) * KDIM + sch * 8;
      bdst[j] = (u16*)(smem + 32768 + (j * 512 + wid * 64) * 16);
    }

    auto stage = [&](int kt, int slot) {
      int so = slot * 49152;                      // LDS byte offset (elements: /2)
      #pragma unroll
      for (int j = 0; j < 4; ++j)
        gload_lds16(asrc[j] + kt * 64, adst[j] + so / 2);
      #pragma unroll
      for (int j = 0; j < 2; ++j)
        gload_lds16(bsrc[j] + kt * 64, bdst[j] + so / 2);
    };

    f32x4 acc[4][4] = {};

    stage(0, 0);
    stage(1, 1);
    asm volatile("s_waitcnt vmcnt(6)" ::: "memory");
    __builtin_amdgcn_s_barrier();
    __builtin_amdgcn_sched_barrier(0);

    for (int kt = 0; kt < 16; ++kt) {
      if (kt + 2 < 16) stage(kt + 2, (kt + 2) % 3);

      const char* As = smem + (kt % 3) * 49152;
      const char* Bs = As + 32768;

      bf16x8 af[2][4], bfr[2][4];
      #pragma unroll
      for (int kk = 0; kk < 2; ++kk) {
        #pragma unroll
        for (int m = 0; m < 4; ++m) {
          int row = wr * 64 + m * 16 + c;
          af[kk][m] = *(const bf16x8*)(As + (row << 7) + ((((kk << 2) + g) ^ cx) << 4));
        }
        #pragma unroll
        for (int n = 0; n < 4; ++n) {
          int row = wc * 64 + n * 16 + c;
          bfr[kk][n] = *(const bf16x8*)(Bs + (row << 7) + ((((kk << 2) + g) ^ cx) << 4));
        }
      }

      __builtin_amdgcn_s_setprio(1);
      #pragma unroll
      for (int kk = 0; kk < 2; ++kk)
        #pragma unroll
        for (int m = 0; m < 4; ++m)
          #pragma unroll
          for (int n = 0; n < 4; ++n)
            acc[m][n] = __builtin_amdgcn_mfma_f32_16x16x32_bf16(
                af[kk][m], bfr[kk][n], acc[m][n], 0, 0, 0);
      __builtin_amdgcn_s_setprio(0);

      if (kt < 15) {
        if (kt < 14) asm volatile("s_waitcnt vmcnt(6)" ::: "memory");
        else         asm volatile("s_waitcnt vmcnt(0)" ::: "memory");
        __builtin_amdgcn_s_barrier();
        __builtin_amdgcn_sched_barrier(0);
      }
    }

    // routed epilogue
    #pragma unroll
    for (int m = 0; m < 4; ++m) {
      #pragma unroll
      for (int n = 0; n < 4; ++n) {
        int col = bcol + wc * 64 + n * 16 + c;
        float bv = bias[col];
        int h = col / 192;
        int rem = col - h * 192;
        int sec = rem >> 6, d = rem & 63;
        #pragma unroll
        for (int r = 0; r < 4; ++r) {
          int row = brow + wr * 64 + m * 16 + g * 4 + r;
          int b = row >> 10, sl = row & 1023;
          float v = acc[m][n][r] + bv;
          if (sec == 0)
            Qh[((size_t)(b * NH + h) * SDIM + sl) * HDIM + d] = f2bf(v * 0.125f);
          else if (sec == 1)
            Kh[((size_t)(b * NH + h) * SDIM + sl) * HDIM + d] = f2bf(v);
          else
            Vt[((size_t)(b * NH + h) * HDIM + d) * SDIM + sl] = f2bf(v);
        }
      }
    }
  } else {
    // ---------- wm3 part: 2 tiles per block, 512 threads ----------
    const int wmid = grp * 4 + (r7 - 3);          // 0..511
    const size_t SS = (size_t)SDIM * SDIM;
    int   (*mt)[68] = (int(*)[68])smem;
    float (*wt)[68] = (float(*)[68])(smem + 17408);

    #pragma unroll
    for (int tt = 0; tt < 2; ++tt) {
      const int id = wmid * 2 + tt;               // 0..1023
      const int kt = id & 15, qt = (id >> 4) & 15, b = id >> 8;
      const int q0 = qt * 64, k0 = kt * 64;
      if (tt) __syncthreads();                    // smem reuse guard

      #pragma unroll
      for (int j = 0; j < 2; ++j) {
        int idx = j * 512 + tid;
        int row = idx >> 4, c4 = idx & 15;
        int4 m4 = *(const int4*)(mask + (size_t)b * SS + (size_t)(q0 + row) * SDIM + k0 + c4 * 4);
        mt[row][c4 * 4 + 0] = m4.x; mt[row][c4 * 4 + 1] = m4.y;
        mt[row][c4 * 4 + 2] = m4.z; mt[row][c4 * 4 + 3] = m4.w;
        float4 w4 = *(const float4*)(wts + (size_t)b * SS + (size_t)(k0 + row) * SDIM + q0 + c4 * 4);
        wt[row][c4 * 4 + 0] = w4.x; wt[row][c4 * 4 + 1] = w4.y;
        wt[row][c4 * 4 + 2] = w4.z; wt[row][c4 * 4 + 3] = w4.w;
      }
      __syncthreads();

      const int st2 = tid >> 6, lane = tid & 63, g2 = lane >> 4, c2 = lane & 15;
      const int st = st2 & 3, wh = st2 >> 2;
      const int kl = st * 16 + c2;
      #pragma unroll
      for (int wq = 0; wq < 2; ++wq) {
        int wid2 = wh * 2 + wq;
        ushort4 o;
        u16* oe = (u16*)&o;
        #pragma unroll
        for (int r = 0; r < 4; ++r) {
          int ql = wid2 * 16 + g2 * 4 + r;
          oe[r] = mt[ql][kl] ? f2bf(wt[kl][ql]) : (u16)0;
        }
        size_t off = (((((size_t)b * 16 + qt) * 4 + wid2) * 16 + kt) * 4 + st) * 256 + (g2 * 16 + c2) * 4;
        *(ushort4*)(wm3 + off) = o;
      }
    }
  }
}

// ---------------- GEMM2 (swizzled LDS, 2-phase 128^2) ----------------
__global__ __launch_bounds__(256) void gemm_bt(
    const u16* __restrict__ A, const u16* __restrict__ Bm,
    const float* __restrict__ bias, float* __restrict__ C,
    int M, int N, int K)
{
  __shared__ u16 As[128 * 64];
  __shared__ u16 Bs[128 * 64];
  const int tid = threadIdx.x;
  const int wid = tid >> 6, lane = tid & 63;
  const int g = lane >> 4, c = lane & 15, cx = c & 7;
  const int wrow = (wid >> 1) * 64, wcol = (wid & 1) * 64;
  const int brow = blockIdx.x * 128, bcol = blockIdx.y * 128;

  const u16* asrc[4]; const u16* bsrc[4]; u16* adst[4]; u16* bdst[4];
  #pragma unroll
  for (int j = 0; j < 4; ++j) {
    int ci = j * 256 + tid;
    int row = ci >> 3, sch = (ci & 7) ^ (row & 7);
    asrc[j] = A  + (size_t)(brow + row) * K + sch * 8;
    bsrc[j] = Bm + (size_t)(bcol + row) * K + sch * 8;
    adst[j] = As + (j * 256 + wid * 64) * 8;
    bdst[j] = Bs + (j * 256 + wid * 64) * 8;
  }

  f32x4 acc[4][4] = {};
  const char* Asc = (const char*)As;
  const char* Bsc = (const char*)Bs;

  for (int kt = 0; kt < K / 64; ++kt) {
    #pragma unroll
    for (int j = 0; j < 4; ++j) {
      gload_lds16(asrc[j] + kt * 64, adst[j]);
      gload_lds16(bsrc[j] + kt * 64, bdst[j]);
    }
    __syncthreads();

    bf16x8 af[2][4], bfr[2][4];
    #pragma unroll
    for (int kk = 0; kk < 2; ++kk)
      #pragma unroll
      for (int i = 0; i < 4; ++i) {
        int cha = ((kk << 2) + g) ^ cx;
        af[kk][i]  = *(const bf16x8*)(Asc + ((wrow + i * 16 + c) << 7) + (cha << 4));
        bfr[kk][i] = *(const bf16x8*)(Bsc + ((wcol + i * 16 + c) << 7) + (cha << 4));
      }
    #pragma unroll
    for (int kk = 0; kk < 2; ++kk)
      #pragma unroll
      for (int mi = 0; mi < 4; ++mi)
        #pragma unroll
        for (int ni = 0; ni < 4; ++ni)
          acc[mi][ni] = __builtin_amdgcn_mfma_f32_16x16x32_bf16(
              af[kk][mi], bfr[kk][ni], acc[mi][ni], 0, 0, 0);
    __syncthreads();
  }

  #pragma unroll
  for (int mi = 0; mi < 4; ++mi)
    #pragma unroll
    for (int ni = 0; ni < 4; ++ni) {
      int col = bcol + wcol + ni * 16 + c;
      float bv = bias[col];
      #pragma unroll
      for (int r = 0; r < 4; ++r) {
        int row = brow + wrow + mi * 16 + g * 4 + r;
        C[(size_t)row * N + col] = acc[mi][ni][r] + bv;
      }
    }
}

// ---------------- attention: LDS-staged, double-buffered, coalesced ----------------
__global__ __launch_bounds__(256, 3) void attn_kernel(
    const u16* __restrict__ Qh, const u16* __restrict__ Kh, const u16* __restrict__ Vt,
    const u16* __restrict__ wm3, u16* __restrict__ vals)
{
  int bid = blockIdx.x;
  int swz = (bid & 7) * 128 + (bid >> 3);
  const int qt = swz & 15, bh = swz >> 4;
  const int h = bh & 15, b = bh >> 4;

  const int tid = threadIdx.x;
  const int wid = tid >> 6, lane = tid & 63;
  const int g = lane >> 4, c = lane & 15;
  const int qloc = qt * 64 + wid * 16;

  __shared__ u16 Kb[2][4096];
  __shared__ u16 Vb[2][4096];
  __shared__ u16 Plds[4][16 * 72];
  char* pw = (char*)&Plds[wid][0];

  const u16* qp = Qh + ((size_t)bh * SDIM + qloc + c) * HDIM;
  bf16x8 qa0 = *(const bf16x8*)(qp + g * 8);
  bf16x8 qa1 = *(const bf16x8*)(qp + 32 + g * 8);

  const u16* kbase = Kh + (size_t)bh * SDIM * HDIM;
  const u16* vbase = Vt + (size_t)bh * HDIM * SDIM;
  const u16* wbase = wm3 + ((((size_t)(b * 16 + qt) * 4 + wid) * 16) * 4) * 256 + (g * 16 + c) * 4;

  float l_run[4] = {0.f, 0.f, 0.f, 0.f};
  f32x4 acc_o[4] = {};
  const int xr = (c & 8) << 2;
  const int cx = c & 7;

  auto stage = [&](int buf, int kt) {
    const int k0 = kt * 64;
    #pragma unroll
    for (int j = 0; j < 2; ++j) {
      int i = j * 256 + tid;
      int row = i >> 3, sch = (i & 7) ^ (row & 7);
      gload_lds16(kbase + (size_t)(k0 + row) * HDIM + sch * 8,
                  &Kb[buf][(size_t)(j * 256 + wid * 64) * 8]);
      gload_lds16(vbase + (size_t)row * SDIM + k0 + sch * 8,
                  &Vb[buf][(size_t)(j * 256 + wid * 64) * 8]);
    }
  };

  stage(0, 0);
  __syncthreads();
  int cur = 0;

  for (int kt = 0; kt < 16; ++kt) {
    if (kt < 15) stage(cur ^ 1, kt + 1);

    ushort4 w4[4];
    #pragma unroll
    for (int st = 0; st < 4; ++st)
      w4[st] = *(const ushort4*)(wbase + (size_t)(kt * 4 + st) * 256);

    const char* kb = (const char*)&Kb[cur][0];
    const char* vb = (const char*)&Vb[cur][0];

    f32x4 sc[4];
    #pragma unroll
    for (int st = 0; st < 4; ++st) {
      int ro = (st * 16 + c) * 128;
      bf16x8 kb0 = *(const bf16x8*)(kb + ro + ((g ^ cx) << 4));
      bf16x8 kb1 = *(const bf16x8*)(kb + ro + (((4 + g) ^ cx) << 4));
      f32x4 z = {};
      z = __builtin_amdgcn_mfma_f32_16x16x32_bf16(qa0, kb0, z, 0, 0, 0);
      z = __builtin_amdgcn_mfma_f32_16x16x32_bf16(qa1, kb1, z, 0, 0, 0);
      sc[st] = z;
    }

    bf16x8 vb0[4], vb1[4];
    #pragma unroll
    for (int dt = 0; dt < 4; ++dt) {
      int ro = (dt * 16 + c) * 128;
      vb0[dt] = *(const bf16x8*)(vb + ro + ((g ^ cx) << 4));
      vb1[dt] = *(const bf16x8*)(vb + ro + (((4 + g) ^ cx) << 4));
    }

    #pragma unroll
    for (int st = 0; st < 4; ++st) {
      #pragma unroll
      for (int r = 0; r < 4; ++r) {
        float w = bf2f(((const u16*)&w4[st])[r]);
        float p = w * __expf(sc[st][r]);
        u16 pb = f2bf(p);
        l_run[r] += bf2f(pb);
        int row = g * 4 + r;
        int colb = (st * 16 + c) * 2;
        *(u16*)(pw + row * 144 + (colb ^ ((row & 8) << 2))) = pb;
      }
    }

    bf16x8 pa0 = *(const bf16x8*)(pw + c * 144 + ((g * 16) ^ xr));
    bf16x8 pa1 = *(const bf16x8*)(pw + c * 144 + ((64 + g * 16) ^ xr));

    #pragma unroll
    for (int dt = 0; dt < 4; ++dt) {
      acc_o[dt] = __builtin_amdgcn_mfma_f32_16x16x32_bf16(pa0, vb0[dt], acc_o[dt], 0, 0, 0);
      acc_o[dt] = __builtin_amdgcn_mfma_f32_16x16x32_bf16(pa1, vb1[dt], acc_o[dt], 0, 0, 0);
    }

    __syncthreads();
    cur ^= 1;
  }

  #pragma unroll
  for (int r = 0; r < 4; ++r) {
    #pragma unroll
    for (int o = 1; o < 16; o <<= 1) l_run[r] += __shfl_xor(l_run[r], o);
  }
  float inv[4];
  #pragma unroll
  for (int r = 0; r < 4; ++r) inv[r] = 1.0f / l_run[r];

  #pragma unroll
  for (int dt = 0; dt < 4; ++dt)
    #pragma unroll
    for (int r = 0; r < 4; ++r) {
      int row = b * SDIM + qloc + g * 4 + r;
      vals[(size_t)row * EMB + h * HDIM + dt * 16 + c] = f2bf(acc_o[dt][r] * inv[r]);
    }
}

extern "C" void kernel_launch(void* const* d_in, const int* in_sizes, int n_in,
                              void* d_out, int out_size, void* d_ws, size_t ws_size,
                              hipStream_t stream) {
  const float* x     = (const float*)d_in[0];
  const int*   mask  = (const int*)d_in[1];
  const float* wts   = (const float*)d_in[2];
  const float* W_qkv = (const float*)d_in[3];
  const float* b_qkv = (const float*)d_in[4];
  const float* W_o   = (const float*)d_in[5];
  const float* b_o   = (const float*)d_in[6];
  float* out = (float*)d_out;

  char* ws = (char*)d_ws;
  u16* xb   = (u16*)(ws);                     //  8 MB x bf16
  u16* wqb  = (u16*)(ws + (8ull  << 20));     //  6 MB W_qkv bf16
  u16* wob  = (u16*)(ws + (14ull << 20));     //  2 MB W_o bf16
  u16* Qh   = (u16*)(ws + (16ull << 20));     //  8 MB [bh][s][64]
  u16* Kh   = (u16*)(ws + (24ull << 20));     //  8 MB [bh][s][64]
  u16* Vt   = (u16*)(ws + (32ull << 20));     //  8 MB [bh][64][s]
  u16* valb = (u16*)(ws + (40ull << 20));     //  8 MB attn out bf16
  u16* wm3b = (u16*)d_out;                    //  8 MB scratch in d_out (overwritten by gemm_bt)

  cvt3_kernel<<<2048, 256, 0, stream>>>(x, W_qkv, W_o, xb, wqb, wob);

  gemm_qkv_wm3<<<896, 512, 0, stream>>>(xb, wqb, b_qkv, Qh, Kh, Vt, mask, wts, wm3b);

  attn_kernel<<<1024, 256, 0, stream>>>(Qh, Kh, Vt, wm3b, valb);

  dim3 g3(32, 8);
  gemm_bt<<<g3, 256, 0, stream>>>(valb, wob, b_o, out, BATCH * SDIM, EMB, KDIM);
}

// Round 6
// 125.467 us; speedup vs baseline: 1.9827x; 1.0873x over previous
//
#include <hip/hip_runtime.h>
#include <hip/hip_bf16.h>
#include <stdint.h>

#define SDIM 1024
#define BATCH 4
#define NH 16
#define HDIM 64
#define KDIM 1024
#define N_QKV 3072
#define EMB 1024

typedef uint16_t u16;
typedef __attribute__((ext_vector_type(4))) float f32x4;
typedef __attribute__((ext_vector_type(8))) short bf16x8;
typedef __attribute__((ext_vector_type(8))) unsigned short u16x8;

__device__ __forceinline__ u16 f2bf(float f) {
  union { float f; uint32_t u; } x; x.f = f;
  uint32_t r = x.u + 0x7FFFu + ((x.u >> 16) & 1u);
  return (u16)(r >> 16);
}

__device__ __forceinline__ float bf2f(u16 b) {
  union { uint32_t u; float f; } x; x.u = ((uint32_t)b) << 16;
  return x.f;
}

__device__ __forceinline__ void gload_lds16(const u16* g, u16* l) {
  __builtin_amdgcn_global_load_lds(
      (const __attribute__((address_space(1))) unsigned int*)g,
      (__attribute__((address_space(3))) unsigned int*)l, 16, 0, 0);
}

// ---------------- merged f32 -> bf16 conversion ----------------
#define N8_X  524288
#define N8_WQ 393216
#define N8_WO 131072
__global__ void cvt3_kernel(const float* __restrict__ a, const float* __restrict__ b,
                            const float* __restrict__ c,
                            u16* __restrict__ oa, u16* __restrict__ ob, u16* __restrict__ oc) {
  const int total = N8_X + N8_WQ + N8_WO;
  int stride = gridDim.x * blockDim.x;
  for (int i = blockIdx.x * blockDim.x + threadIdx.x; i < total; i += stride) {
    const float* s; u16* d; int j;
    if (i < N8_X)            { s = a; d = oa; j = i; }
    else if (i < N8_X + N8_WQ){ s = b; d = ob; j = i - N8_X; }
    else                     { s = c; d = oc; j = i - N8_X - N8_WQ; }
    const float4* s4 = (const float4*)s + (size_t)j * 2;
    float4 u = s4[0], v = s4[1];
    u16x8 o;
    o[0] = f2bf(u.x); o[1] = f2bf(u.y); o[2] = f2bf(u.z); o[3] = f2bf(u.w);
    o[4] = f2bf(v.x); o[5] = f2bf(v.y); o[6] = f2bf(v.z); o[7] = f2bf(v.w);
    ((u16x8*)d)[j] = o;
  }
}

// ---------------- GEMM1: 256x256x64 2-phase, single dispatch round + wm3 ----------------
// blocks 0..191: GEMM tiles (16 M x 12 N). blocks 192..703: wm3 (512 x 2 tiles).
// LDS: 2 slots x (A 256x64 + B 256x64) bf16 = 2 x 64KB = 128KB.
__global__ __launch_bounds__(512, 2) void gemm_qkv_wm3(
    const u16* __restrict__ A, const u16* __restrict__ Bm,
    const float* __restrict__ bias,
    u16* __restrict__ Qh, u16* __restrict__ Kh, u16* __restrict__ Vt,
    const int* __restrict__ mask, const float* __restrict__ wts, u16* __restrict__ wm3)
{
  __shared__ char smem[131072];
  const int tid = threadIdx.x;

  if (blockIdx.x < 192) {
    // ---------- GEMM part ----------
    const int gid = blockIdx.x;
    const int brow = (gid & 15) * 256, bcol = (gid >> 4) * 256;
    const int wid = tid >> 6, lane = tid & 63;
    const int g = lane >> 4, c = lane & 15, cx = c & 7;
    const int wr = wid >> 2, wc = wid & 3;        // 2 M-groups x 4 N-groups

    // staging: A 2048 chunks (256 rows x 8), B same; 4+4 loads/thread
    const u16* asrc[4]; const u16* bsrc[4]; int doff[4];
    #pragma unroll
    for (int j = 0; j < 4; ++j) {
      int i = j * 512 + tid;
      int row = i >> 3, sch = (i & 7) ^ (row & 7);
      asrc[j] = A  + (size_t)(brow + row) * KDIM + sch * 8;
      bsrc[j] = Bm + (size_t)(bcol + row) * KDIM + sch * 8;
      doff[j] = (j * 512 + wid * 64) * 16;        // wave-uniform LDS byte offset
    }

    auto stage = [&](int kt, int slot) {
      char* base = smem + slot * 65536;
      #pragma unroll
      for (int j = 0; j < 4; ++j)
        gload_lds16(asrc[j] + kt * 64, (u16*)(base + doff[j]));
      #pragma unroll
      for (int j = 0; j < 4; ++j)
        gload_lds16(bsrc[j] + kt * 64, (u16*)(base + 32768 + doff[j]));
    };

    f32x4 acc[8][4] = {};

    stage(0, 0);
    __syncthreads();

    for (int kt = 0; kt < 16; ++kt) {
      if (kt < 15) stage(kt + 1, (kt + 1) & 1);

      const char* As = smem + (kt & 1) * 65536;
      const char* Bs = As + 32768;

      #pragma unroll
      for (int kk = 0; kk < 2; ++kk) {
        bf16x8 af[8], bfr[4];
        #pragma unroll
        for (int m = 0; m < 8; ++m) {
          int row = wr * 128 + m * 16 + c;
          af[m] = *(const bf16x8*)(As + (row << 7) + ((((kk << 2) + g) ^ cx) << 4));
        }
        #pragma unroll
        for (int n = 0; n < 4; ++n) {
          int row = wc * 64 + n * 16 + c;
          bfr[n] = *(const bf16x8*)(Bs + (row << 7) + ((((kk << 2) + g) ^ cx) << 4));
        }
        __builtin_amdgcn_s_setprio(1);
        #pragma unroll
        for (int m = 0; m < 8; ++m)
          #pragma unroll
          for (int n = 0; n < 4; ++n)
            acc[m][n] = __builtin_amdgcn_mfma_f32_16x16x32_bf16(
                af[m], bfr[n], acc[m][n], 0, 0, 0);
        __builtin_amdgcn_s_setprio(0);
      }
      __syncthreads();
    }

    // routed epilogue
    #pragma unroll
    for (int m = 0; m < 8; ++m) {
      #pragma unroll
      for (int n = 0; n < 4; ++n) {
        int col = bcol + wc * 64 + n * 16 + c;
        float bv = bias[col];
        int h = col / 192;
        int rem = col - h * 192;
        int sec = rem >> 6, d = rem & 63;
        #pragma unroll
        for (int r = 0; r < 4; ++r) {
          int row = brow + wr * 128 + m * 16 + g * 4 + r;
          int b = row >> 10, sl = row & 1023;
          float v = acc[m][n][r] + bv;
          if (sec == 0)
            Qh[((size_t)(b * NH + h) * SDIM + sl) * HDIM + d] = f2bf(v * 0.125f);
          else if (sec == 1)
            Kh[((size_t)(b * NH + h) * SDIM + sl) * HDIM + d] = f2bf(v);
          else
            Vt[((size_t)(b * NH + h) * HDIM + d) * SDIM + sl] = f2bf(v);
        }
      }
    }
  } else {
    // ---------- wm3 part: 2 tiles per block, 512 threads ----------
    const int wmid = blockIdx.x - 192;            // 0..511
    const size_t SS = (size_t)SDIM * SDIM;
    int   (*mt)[68] = (int(*)[68])smem;
    float (*wt)[68] = (float(*)[68])(smem + 17408);

    #pragma unroll
    for (int tt = 0; tt < 2; ++tt) {
      const int id = wmid * 2 + tt;               // 0..1023
      const int kt = id & 15, qt = (id >> 4) & 15, b = id >> 8;
      const int q0 = qt * 64, k0 = kt * 64;
      if (tt) __syncthreads();                    // smem reuse guard

      #pragma unroll
      for (int j = 0; j < 2; ++j) {
        int idx = j * 512 + tid;
        int row = idx >> 4, c4 = idx & 15;
        int4 m4 = *(const int4*)(mask + (size_t)b * SS + (size_t)(q0 + row) * SDIM + k0 + c4 * 4);
        mt[row][c4 * 4 + 0] = m4.x; mt[row][c4 * 4 + 1] = m4.y;
        mt[row][c4 * 4 + 2] = m4.z; mt[row][c4 * 4 + 3] = m4.w;
        float4 w4 = *(const float4*)(wts + (size_t)b * SS + (size_t)(k0 + row) * SDIM + q0 + c4 * 4);
        wt[row][c4 * 4 + 0] = w4.x; wt[row][c4 * 4 + 1] = w4.y;
        wt[row][c4 * 4 + 2] = w4.z; wt[row][c4 * 4 + 3] = w4.w;
      }
      __syncthreads();

      const int st2 = tid >> 6, lane = tid & 63, g2 = lane >> 4, c2 = lane & 15;
      const int st = st2 & 3, wh = st2 >> 2;
      const int kl = st * 16 + c2;
      #pragma unroll
      for (int wq = 0; wq < 2; ++wq) {
        int wid2 = wh * 2 + wq;
        ushort4 o;
        u16* oe = (u16*)&o;
        #pragma unroll
        for (int r = 0; r < 4; ++r) {
          int ql = wid2 * 16 + g2 * 4 + r;
          oe[r] = mt[ql][kl] ? f2bf(wt[kl][ql]) : (u16)0;
        }
        size_t off = (((((size_t)b * 16 + qt) * 4 + wid2) * 16 + kt) * 4 + st) * 256 + (g2 * 16 + c2) * 4;
        *(ushort4*)(wm3 + off) = o;
      }
    }
  }
}

// ---------------- GEMM2 (swizzled LDS, 2-phase 128^2) ----------------
__global__ __launch_bounds__(256) void gemm_bt(
    const u16* __restrict__ A, const u16* __restrict__ Bm,
    const float* __restrict__ bias, float* __restrict__ C,
    int M, int N, int K)
{
  __shared__ u16 As[128 * 64];
  __shared__ u16 Bs[128 * 64];
  const int tid = threadIdx.x;
  const int wid = tid >> 6, lane = tid & 63;
  const int g = lane >> 4, c = lane & 15, cx = c & 7;
  const int wrow = (wid >> 1) * 64, wcol = (wid & 1) * 64;
  const int brow = blockIdx.x * 128, bcol = blockIdx.y * 128;

  const u16* asrc[4]; const u16* bsrc[4]; u16* adst[4]; u16* bdst[4];
  #pragma unroll
  for (int j = 0; j < 4; ++j) {
    int ci = j * 256 + tid;
    int row = ci >> 3, sch = (ci & 7) ^ (row & 7);
    asrc[j] = A  + (size_t)(brow + row) * K + sch * 8;
    bsrc[j] = Bm + (size_t)(bcol + row) * K + sch * 8;
    adst[j] = As + (j * 256 + wid * 64) * 8;
    bdst[j] = Bs + (j * 256 + wid * 64) * 8;
  }

  f32x4 acc[4][4] = {};
  const char* Asc = (const char*)As;
  const char* Bsc = (const char*)Bs;

  for (int kt = 0; kt < K / 64; ++kt) {
    #pragma unroll
    for (int j = 0; j < 4; ++j) {
      gload_lds16(asrc[j] + kt * 64, adst[j]);
      gload_lds16(bsrc[j] + kt * 64, bdst[j]);
    }
    __syncthreads();

    bf16x8 af[2][4], bfr[2][4];
    #pragma unroll
    for (int kk = 0; kk < 2; ++kk)
      #pragma unroll
      for (int i = 0; i < 4; ++i) {
        int cha = ((kk << 2) + g) ^ cx;
        af[kk][i]  = *(const bf16x8*)(Asc + ((wrow + i * 16 + c) << 7) + (cha << 4));
        bfr[kk][i] = *(const bf16x8*)(Bsc + ((wcol + i * 16 + c) << 7) + (cha << 4));
      }
    #pragma unroll
    for (int kk = 0; kk < 2; ++kk)
      #pragma unroll
      for (int mi = 0; mi < 4; ++mi)
        #pragma unroll
        for (int ni = 0; ni < 4; ++ni)
          acc[mi][ni] = __builtin_amdgcn_mfma_f32_16x16x32_bf16(
              af[kk][mi], bfr[kk][ni], acc[mi][ni], 0, 0, 0);
    __syncthreads();
  }

  #pragma unroll
  for (int mi = 0; mi < 4; ++mi)
    #pragma unroll
    for (int ni = 0; ni < 4; ++ni) {
      int col = bcol + wcol + ni * 16 + c;
      float bv = bias[col];
      #pragma unroll
      for (int r = 0; r < 4; ++r) {
        int row = brow + wrow + mi * 16 + g * 4 + r;
        C[(size_t)row * N + col] = acc[mi][ni][r] + bv;
      }
    }
}

// ---------------- attention: LDS-staged, double-buffered, coalesced ----------------
__global__ __launch_bounds__(256, 3) void attn_kernel(
    const u16* __restrict__ Qh, const u16* __restrict__ Kh, const u16* __restrict__ Vt,
    const u16* __restrict__ wm3, u16* __restrict__ vals)
{
  int bid = blockIdx.x;
  int swz = (bid & 7) * 128 + (bid >> 3);
  const int qt = swz & 15, bh = swz >> 4;
  const int h = bh & 15, b = bh >> 4;

  const int tid = threadIdx.x;
  const int wid = tid >> 6, lane = tid & 63;
  const int g = lane >> 4, c = lane & 15;
  const int qloc = qt * 64 + wid * 16;

  __shared__ u16 Kb[2][4096];
  __shared__ u16 Vb[2][4096];
  __shared__ u16 Plds[4][16 * 72];
  char* pw = (char*)&Plds[wid][0];

  const u16* qp = Qh + ((size_t)bh * SDIM + qloc + c) * HDIM;
  bf16x8 qa0 = *(const bf16x8*)(qp + g * 8);
  bf16x8 qa1 = *(const bf16x8*)(qp + 32 + g * 8);

  const u16* kbase = Kh + (size_t)bh * SDIM * HDIM;
  const u16* vbase = Vt + (size_t)bh * HDIM * SDIM;
  const u16* wbase = wm3 + ((((size_t)(b * 16 + qt) * 4 + wid) * 16) * 4) * 256 + (g * 16 + c) * 4;

  float l_run[4] = {0.f, 0.f, 0.f, 0.f};
  f32x4 acc_o[4] = {};
  const int xr = (c & 8) << 2;
  const int cx = c & 7;

  auto stage = [&](int buf, int kt) {
    const int k0 = kt * 64;
    #pragma unroll
    for (int j = 0; j < 2; ++j) {
      int i = j * 256 + tid;
      int row = i >> 3, sch = (i & 7) ^ (row & 7);
      gload_lds16(kbase + (size_t)(k0 + row) * HDIM + sch * 8,
                  &Kb[buf][(size_t)(j * 256 + wid * 64) * 8]);
      gload_lds16(vbase + (size_t)row * SDIM + k0 + sch * 8,
                  &Vb[buf][(size_t)(j * 256 + wid * 64) * 8]);
    }
  };

  stage(0, 0);
  __syncthreads();
  int cur = 0;

  for (int kt = 0; kt < 16; ++kt) {
    if (kt < 15) stage(cur ^ 1, kt + 1);

    ushort4 w4[4];
    #pragma unroll
    for (int st = 0; st < 4; ++st)
      w4[st] = *(const ushort4*)(wbase + (size_t)(kt * 4 + st) * 256);

    const char* kb = (const char*)&Kb[cur][0];
    const char* vb = (const char*)&Vb[cur][0];

    f32x4 sc[4];
    #pragma unroll
    for (int st = 0; st < 4; ++st) {
      int ro = (st * 16 + c) * 128;
      bf16x8 kb0 = *(const bf16x8*)(kb + ro + ((g ^ cx) << 4));
      bf16x8 kb1 = *(const bf16x8*)(kb + ro + (((4 + g) ^ cx) << 4));
      f32x4 z = {};
      z = __builtin_amdgcn_mfma_f32_16x16x32_bf16(qa0, kb0, z, 0, 0, 0);
      z = __builtin_amdgcn_mfma_f32_16x16x32_bf16(qa1, kb1, z, 0, 0, 0);
      sc[st] = z;
    }

    bf16x8 vb0[4], vb1[4];
    #pragma unroll
    for (int dt = 0; dt < 4; ++dt) {
      int ro = (dt * 16 + c) * 128;
      vb0[dt] = *(const bf16x8*)(vb + ro + ((g ^ cx) << 4));
      vb1[dt] = *(const bf16x8*)(vb + ro + (((4 + g) ^ cx) << 4));
    }

    #pragma unroll
    for (int st = 0; st < 4; ++st) {
      #pragma unroll
      for (int r = 0; r < 4; ++r) {
        float w = bf2f(((const u16*)&w4[st])[r]);
        float p = w * __expf(sc[st][r]);
        u16 pb = f2bf(p);
        l_run[r] += bf2f(pb);
        int row = g * 4 + r;
        int colb = (st * 16 + c) * 2;
        *(u16*)(pw + row * 144 + (colb ^ ((row & 8) << 2))) = pb;
      }
    }

    bf16x8 pa0 = *(const bf16x8*)(pw + c * 144 + ((g * 16) ^ xr));
    bf16x8 pa1 = *(const bf16x8*)(pw + c * 144 + ((64 + g * 16) ^ xr));

    #pragma unroll
    for (int dt = 0; dt < 4; ++dt) {
      acc_o[dt] = __builtin_amdgcn_mfma_f32_16x16x32_bf16(pa0, vb0[dt], acc_o[dt], 0, 0, 0);
      acc_o[dt] = __builtin_amdgcn_mfma_f32_16x16x32_bf16(pa1, vb1[dt], acc_o[dt], 0, 0, 0);
    }

    __syncthreads();
    cur ^= 1;
  }

  #pragma unroll
  for (int r = 0; r < 4; ++r) {
    #pragma unroll
    for (int o = 1; o < 16; o <<= 1) l_run[r] += __shfl_xor(l_run[r], o);
  }
  float inv[4];
  #pragma unroll
  for (int r = 0; r < 4; ++r) inv[r] = 1.0f / l_run[r];

  #pragma unroll
  for (int dt = 0; dt < 4; ++dt)
    #pragma unroll
    for (int r = 0; r < 4; ++r) {
      int row = b * SDIM + qloc + g * 4 + r;
      vals[(size_t)row * EMB + h * HDIM + dt * 16 + c] = f2bf(acc_o[dt][r] * inv[r]);
    }
}

extern "C" void kernel_launch(void* const* d_in, const int* in_sizes, int n_in,
                              void* d_out, int out_size, void* d_ws, size_t ws_size,
                              hipStream_t stream) {
  const float* x     = (const float*)d_in[0];
  const int*   mask  = (const int*)d_in[1];
  const float* wts   = (const float*)d_in[2];
  const float* W_qkv = (const float*)d_in[3];
  const float* b_qkv = (const float*)d_in[4];
  const float* W_o   = (const float*)d_in[5];
  const float* b_o   = (const float*)d_in[6];
  float* out = (float*)d_out;

  char* ws = (char*)d_ws;
  u16* xb   = (u16*)(ws);                     //  8 MB x bf16
  u16* wqb  = (u16*)(ws + (8ull  << 20));     //  6 MB W_qkv bf16
  u16* wob  = (u16*)(ws + (14ull << 20));     //  2 MB W_o bf16
  u16* Qh   = (u16*)(ws + (16ull << 20));     //  8 MB [bh][s][64]
  u16* Kh   = (u16*)(ws + (24ull << 20));     //  8 MB [bh][s][64]
  u16* Vt   = (u16*)(ws + (32ull << 20));     //  8 MB [bh][64][s]
  u16* valb = (u16*)(ws + (40ull << 20));     //  8 MB attn out bf16
  u16* wm3b = (u16*)d_out;                    //  8 MB scratch in d_out (overwritten by gemm_bt)

  cvt3_kernel<<<2048, 256, 0, stream>>>(x, W_qkv, W_o, xb, wqb, wob);

  gemm_qkv_wm3<<<704, 512, 0, stream>>>(xb, wqb, b_qkv, Qh, Kh, Vt, mask, wts, wm3b);

  attn_kernel<<<1024, 256, 0, stream>>>(Qh, Kh, Vt, wm3b, valb);

  dim3 g3(32, 8);
  gemm_bt<<<g3, 256, 0, stream>>>(valb, wob, b_o, out, BATCH * SDIM, EMB, KDIM);
}

// Round 7
// 108.486 us; speedup vs baseline: 2.2931x; 1.1565x over previous
//
#include <hip/hip_runtime.h>
#include <hip/hip_bf16.h>
#include <stdint.h>

#define SDIM 1024
#define BATCH 4
#define NH 16
#define HDIM 64
#define KDIM 1024
#define N_QKV 3072
#define EMB 1024

typedef uint16_t u16;
typedef __attribute__((ext_vector_type(4))) float f32x4;
typedef __attribute__((ext_vector_type(8))) short bf16x8;
typedef __attribute__((ext_vector_type(8))) unsigned short u16x8;

__device__ __forceinline__ u16 f2bf(float f) {
  union { float f; uint32_t u; } x; x.f = f;
  uint32_t r = x.u + 0x7FFFu + ((x.u >> 16) & 1u);
  return (u16)(r >> 16);
}

__device__ __forceinline__ float bf2f(u16 b) {
  union { uint32_t u; float f; } x; x.u = ((uint32_t)b) << 16;
  return x.f;
}

__device__ __forceinline__ void gload_lds16(const u16* g, u16* l) {
  __builtin_amdgcn_global_load_lds(
      (const __attribute__((address_space(1))) unsigned int*)g,
      (__attribute__((address_space(3))) unsigned int*)l, 16, 0, 0);
}

// ---------------- merged f32 -> bf16 conversion ----------------
#define N8_X  524288
#define N8_WQ 393216
#define N8_WO 131072
__global__ void cvt3_kernel(const float* __restrict__ a, const float* __restrict__ b,
                            const float* __restrict__ c,
                            u16* __restrict__ oa, u16* __restrict__ ob, u16* __restrict__ oc) {
  const int total = N8_X + N8_WQ + N8_WO;
  int stride = gridDim.x * blockDim.x;
  for (int i = blockIdx.x * blockDim.x + threadIdx.x; i < total; i += stride) {
    const float* s; u16* d; int j;
    if (i < N8_X)            { s = a; d = oa; j = i; }
    else if (i < N8_X + N8_WQ){ s = b; d = ob; j = i - N8_X; }
    else                     { s = c; d = oc; j = i - N8_X - N8_WQ; }
    const float4* s4 = (const float4*)s + (size_t)j * 2;
    float4 u = s4[0], v = s4[1];
    u16x8 o;
    o[0] = f2bf(u.x); o[1] = f2bf(u.y); o[2] = f2bf(u.z); o[3] = f2bf(u.w);
    o[4] = f2bf(v.x); o[5] = f2bf(v.y); o[6] = f2bf(v.z); o[7] = f2bf(v.w);
    ((u16x8*)d)[j] = o;
  }
}

// ---------------- GEMM1: 256x256x64 2-phase + wm3 (fragment-ordered weights) ----------------
// blocks 0..191: GEMM tiles (16 M x 12 N). blocks 192..703: wm3 (512 x 2 tiles).
// wm3 layout: [b][qt][wid][kt][lane][16] where element e (st=2h+(e>>2), r=e&3, h from e..):
//   value = wm[k = kt*64 + 8*(lane>>4) + 4*((e>>2)&1) + (e&3) + 32*(e>>3)][q = qt*64+wid*16+(lane&15)]
__global__ __launch_bounds__(512, 2) void gemm_qkv_wm3(
    const u16* __restrict__ A, const u16* __restrict__ Bm,
    const float* __restrict__ bias,
    u16* __restrict__ Qh, u16* __restrict__ Kh, u16* __restrict__ Vt,
    const int* __restrict__ mask, const float* __restrict__ wts, u16* __restrict__ wm3)
{
  __shared__ char smem[131072];
  const int tid = threadIdx.x;

  if (blockIdx.x < 192) {
    // ---------- GEMM part ----------
    const int gid = blockIdx.x;
    const int brow = (gid & 15) * 256, bcol = (gid >> 4) * 256;
    const int wid = tid >> 6, lane = tid & 63;
    const int g = lane >> 4, c = lane & 15, cx = c & 7;
    const int wr = wid >> 2, wc = wid & 3;        // 2 M-groups x 4 N-groups

    const u16* asrc[4]; const u16* bsrc[4]; int doff[4];
    #pragma unroll
    for (int j = 0; j < 4; ++j) {
      int i = j * 512 + tid;
      int row = i >> 3, sch = (i & 7) ^ (row & 7);
      asrc[j] = A  + (size_t)(brow + row) * KDIM + sch * 8;
      bsrc[j] = Bm + (size_t)(bcol + row) * KDIM + sch * 8;
      doff[j] = (j * 512 + wid * 64) * 16;
    }

    auto stage = [&](int kt, int slot) {
      char* base = smem + slot * 65536;
      #pragma unroll
      for (int j = 0; j < 4; ++j)
        gload_lds16(asrc[j] + kt * 64, (u16*)(base + doff[j]));
      #pragma unroll
      for (int j = 0; j < 4; ++j)
        gload_lds16(bsrc[j] + kt * 64, (u16*)(base + 32768 + doff[j]));
    };

    f32x4 acc[8][4] = {};

    stage(0, 0);
    __syncthreads();

    for (int kt = 0; kt < 16; ++kt) {
      if (kt < 15) stage(kt + 1, (kt + 1) & 1);

      const char* As = smem + (kt & 1) * 65536;
      const char* Bs = As + 32768;

      #pragma unroll
      for (int kk = 0; kk < 2; ++kk) {
        bf16x8 af[8], bfr[4];
        #pragma unroll
        for (int m = 0; m < 8; ++m) {
          int row = wr * 128 + m * 16 + c;
          af[m] = *(const bf16x8*)(As + (row << 7) + ((((kk << 2) + g) ^ cx) << 4));
        }
        #pragma unroll
        for (int n = 0; n < 4; ++n) {
          int row = wc * 64 + n * 16 + c;
          bfr[n] = *(const bf16x8*)(Bs + (row << 7) + ((((kk << 2) + g) ^ cx) << 4));
        }
        __builtin_amdgcn_s_setprio(1);
        #pragma unroll
        for (int m = 0; m < 8; ++m)
          #pragma unroll
          for (int n = 0; n < 4; ++n)
            acc[m][n] = __builtin_amdgcn_mfma_f32_16x16x32_bf16(
                af[m], bfr[n], acc[m][n], 0, 0, 0);
        __builtin_amdgcn_s_setprio(0);
      }
      __syncthreads();
    }

    #pragma unroll
    for (int m = 0; m < 8; ++m) {
      #pragma unroll
      for (int n = 0; n < 4; ++n) {
        int col = bcol + wc * 64 + n * 16 + c;
        float bv = bias[col];
        int h = col / 192;
        int rem = col - h * 192;
        int sec = rem >> 6, d = rem & 63;
        #pragma unroll
        for (int r = 0; r < 4; ++r) {
          int row = brow + wr * 128 + m * 16 + g * 4 + r;
          int b = row >> 10, sl = row & 1023;
          float v = acc[m][n][r] + bv;
          if (sec == 0)
            Qh[((size_t)(b * NH + h) * SDIM + sl) * HDIM + d] = f2bf(v * 0.125f);
          else if (sec == 1)
            Kh[((size_t)(b * NH + h) * SDIM + sl) * HDIM + d] = f2bf(v);
          else
            Vt[((size_t)(b * NH + h) * HDIM + d) * SDIM + sl] = f2bf(v);
        }
      }
    }
  } else {
    // ---------- wm3 part: 2 tiles per block, 512 threads ----------
    const int wmid = blockIdx.x - 192;            // 0..511
    const size_t SS = (size_t)SDIM * SDIM;
    int   (*mt)[69] = (int(*)[69])smem;             // [q][k]  64x69
    float (*wt)[69] = (float(*)[69])(smem + 17664); // [k][q]  64x69

    #pragma unroll
    for (int tt = 0; tt < 2; ++tt) {
      const int id = wmid * 2 + tt;               // 0..1023
      const int kt = id & 15, qt = (id >> 4) & 15, b = id >> 8;
      const int q0 = qt * 64, k0 = kt * 64;
      if (tt) __syncthreads();

      #pragma unroll
      for (int j = 0; j < 2; ++j) {
        int idx = j * 512 + tid;
        int row = idx >> 4, c4 = idx & 15;
        int4 m4 = *(const int4*)(mask + (size_t)b * SS + (size_t)(q0 + row) * SDIM + k0 + c4 * 4);
        mt[row][c4 * 4 + 0] = m4.x; mt[row][c4 * 4 + 1] = m4.y;
        mt[row][c4 * 4 + 2] = m4.z; mt[row][c4 * 4 + 3] = m4.w;
        float4 w4 = *(const float4*)(wts + (size_t)b * SS + (size_t)(k0 + row) * SDIM + q0 + c4 * 4);
        wt[row][c4 * 4 + 0] = w4.x; wt[row][c4 * 4 + 1] = w4.y;
        wt[row][c4 * 4 + 2] = w4.z; wt[row][c4 * 4 + 3] = w4.w;
      }
      __syncthreads();

      // fragment-ordered write: thread -> (wid2, half, lane)
      const int wid2 = tid >> 7, hf = (tid >> 6) & 1, lane = tid & 63;
      const int g2 = lane >> 4, c2 = lane & 15;
      const int ql = wid2 * 16 + c2;
      u16x8 o;
      #pragma unroll
      for (int e = 0; e < 8; ++e) {
        int kl = 8 * g2 + 4 * (e >> 2) + (e & 3) + 32 * hf;
        o[e] = mt[ql][kl] ? f2bf(wt[kl][ql]) : (u16)0;
      }
      size_t off = ((((size_t)(b * 16 + qt) * 4 + wid2) * 16 + kt)) * 1024 + lane * 16 + hf * 8;
      *(u16x8*)(wm3 + off) = o;
    }
  }
}

// ---------------- GEMM2 (swizzled LDS, 2-phase 128^2) ----------------
__global__ __launch_bounds__(256) void gemm_bt(
    const u16* __restrict__ A, const u16* __restrict__ Bm,
    const float* __restrict__ bias, float* __restrict__ C,
    int M, int N, int K)
{
  __shared__ u16 As[128 * 64];
  __shared__ u16 Bs[128 * 64];
  const int tid = threadIdx.x;
  const int wid = tid >> 6, lane = tid & 63;
  const int g = lane >> 4, c = lane & 15, cx = c & 7;
  const int wrow = (wid >> 1) * 64, wcol = (wid & 1) * 64;
  const int brow = blockIdx.x * 128, bcol = blockIdx.y * 128;

  const u16* asrc[4]; const u16* bsrc[4]; u16* adst[4]; u16* bdst[4];
  #pragma unroll
  for (int j = 0; j < 4; ++j) {
    int ci = j * 256 + tid;
    int row = ci >> 3, sch = (ci & 7) ^ (row & 7);
    asrc[j] = A  + (size_t)(brow + row) * K + sch * 8;
    bsrc[j] = Bm + (size_t)(bcol + row) * K + sch * 8;
    adst[j] = As + (j * 256 + wid * 64) * 8;
    bdst[j] = Bs + (j * 256 + wid * 64) * 8;
  }

  f32x4 acc[4][4] = {};
  const char* Asc = (const char*)As;
  const char* Bsc = (const char*)Bs;

  for (int kt = 0; kt < K / 64; ++kt) {
    #pragma unroll
    for (int j = 0; j < 4; ++j) {
      gload_lds16(asrc[j] + kt * 64, adst[j]);
      gload_lds16(bsrc[j] + kt * 64, bdst[j]);
    }
    __syncthreads();

    bf16x8 af[2][4], bfr[2][4];
    #pragma unroll
    for (int kk = 0; kk < 2; ++kk)
      #pragma unroll
      for (int i = 0; i < 4; ++i) {
        int cha = ((kk << 2) + g) ^ cx;
        af[kk][i]  = *(const bf16x8*)(Asc + ((wrow + i * 16 + c) << 7) + (cha << 4));
        bfr[kk][i] = *(const bf16x8*)(Bsc + ((wcol + i * 16 + c) << 7) + (cha << 4));
      }
    #pragma unroll
    for (int kk = 0; kk < 2; ++kk)
      #pragma unroll
      for (int mi = 0; mi < 4; ++mi)
        #pragma unroll
        for (int ni = 0; ni < 4; ++ni)
          acc[mi][ni] = __builtin_amdgcn_mfma_f32_16x16x32_bf16(
              af[kk][mi], bfr[kk][ni], acc[mi][ni], 0, 0, 0);
    __syncthreads();
  }

  #pragma unroll
  for (int mi = 0; mi < 4; ++mi)
    #pragma unroll
    for (int ni = 0; ni < 4; ++ni) {
      int col = bcol + wcol + ni * 16 + c;
      float bv = bias[col];
      #pragma unroll
      for (int r = 0; r < 4; ++r) {
        int row = brow + wrow + mi * 16 + g * 4 + r;
        C[(size_t)row * N + col] = acc[mi][ni][r] + bv;
      }
    }
}

// ---------------- attention: in-register P (swapped QK^T + K-row permutation) ----------------
// Qh/Kh [bh][s][64] bf16 (Q pre-scaled 1/8), Vt [bh][64][s], wm3 fragment-ordered.
// Per subtile st, QK^T A-operand uses K rows kphys(st,m)=8(m>>2)+4(st&1)+(m&3)+32(st>>1),
// so lane (c,g) ends up holding S[k=8g+4(st&1)+r+32(st>>1)][q=c] -> its own PV A-fragment.
__global__ __launch_bounds__(256, 4) void attn_kernel(
    const u16* __restrict__ Qh, const u16* __restrict__ Kh, const u16* __restrict__ Vt,
    const u16* __restrict__ wm3, u16* __restrict__ vals)
{
  int bid = blockIdx.x;
  int swz = (bid & 7) * 128 + (bid >> 3);
  const int qt = swz & 15, bh = swz >> 4;
  const int h = bh & 15, b = bh >> 4;

  const int tid = threadIdx.x;
  const int wid = tid >> 6, lane = tid & 63;
  const int g = lane >> 4, c = lane & 15;
  const int qloc = qt * 64 + wid * 16;

  __shared__ u16 Kb[2][4096];
  __shared__ u16 Vb[2][4096];

  const u16* qp = Qh + ((size_t)bh * SDIM + qloc + c) * HDIM;
  bf16x8 qa0 = *(const bf16x8*)(qp + g * 8);
  bf16x8 qa1 = *(const bf16x8*)(qp + 32 + g * 8);

  const u16* kbase = Kh + (size_t)bh * SDIM * HDIM;
  const u16* vbase = Vt + (size_t)bh * HDIM * SDIM;
  const u16* wbase = wm3 + (((size_t)(b * 16 + qt) * 4 + wid) * 16) * 1024 + lane * 16;

  float l_run = 0.f;
  f32x4 acc_o[4] = {};

  // swizzle: fsw(row) = ((row ^ (row>>3)) & 7) ^ ((row & 1) << 2)
  auto fsw = [](int row) { return ((row ^ (row >> 3)) & 7) ^ ((row & 1) << 2); };

  // precompute permuted K-row offsets and V-row offsets + their swizzles
  int kro[4], kxr[4], vro[4], vxr[4];
  #pragma unroll
  for (int st = 0; st < 4; ++st) {
    int kr = ((c >> 2) << 3) + ((st & 1) << 2) + (c & 3) + ((st >> 1) << 5);
    kro[st] = kr << 7;
    kxr[st] = fsw(kr);
  }
  #pragma unroll
  for (int dt = 0; dt < 4; ++dt) {
    int vr = dt * 16 + c;
    vro[dt] = vr << 7;
    vxr[dt] = fsw(vr);
  }

  auto stage = [&](int buf, int kt) {
    const int k0 = kt * 64;
    #pragma unroll
    for (int j = 0; j < 2; ++j) {
      int i = j * 256 + tid;
      int row = i >> 3;
      int sch = (i & 7) ^ (((row ^ (row >> 3)) & 7) ^ ((row & 1) << 2));
      gload_lds16(kbase + (size_t)(k0 + row) * HDIM + sch * 8,
                  &Kb[buf][(size_t)(j * 256 + wid * 64) * 8]);
      gload_lds16(vbase + (size_t)row * SDIM + k0 + sch * 8,
                  &Vb[buf][(size_t)(j * 256 + wid * 64) * 8]);
    }
  };

  stage(0, 0);
  __syncthreads();
  int cur = 0;

  for (int kt = 0; kt < 16; ++kt) {
    if (kt < 15) stage(cur ^ 1, kt + 1);

    // fragment-ordered weights: 2x16B contiguous loads
    u16x8 w0 = *(const u16x8*)(wbase + kt * 1024);
    u16x8 w1 = *(const u16x8*)(wbase + kt * 1024 + 8);

    const char* kb = (const char*)&Kb[cur][0];
    const char* vb = (const char*)&Vb[cur][0];

    // swapped QK^T: A = permuted K rows, B = Q
    f32x4 sc[4];
    #pragma unroll
    for (int st = 0; st < 4; ++st) {
      bf16x8 ka0 = *(const bf16x8*)(kb + kro[st] + ((g ^ kxr[st]) << 4));
      bf16x8 ka1 = *(const bf16x8*)(kb + kro[st] + (((4 + g) ^ kxr[st]) << 4));
      f32x4 z = {};
      z = __builtin_amdgcn_mfma_f32_16x16x32_bf16(ka0, qa0, z, 0, 0, 0);
      z = __builtin_amdgcn_mfma_f32_16x16x32_bf16(ka1, qa1, z, 0, 0, 0);
      sc[st] = z;
    }

    // p = w * exp(s), all lane-local; l_run is scalar (one q per lane)
    float p[4][4];
    #pragma unroll
    for (int st = 0; st < 4; ++st) {
      #pragma unroll
      for (int r = 0; r < 4; ++r) {
        u16 wv = (st < 2) ? ((const u16*)&w0)[st * 4 + r]
                          : ((const u16*)&w1)[(st - 2) * 4 + r];
        float pv = bf2f(wv) * __expf(sc[st][r]);
        p[st][r] = pv;
        l_run += pv;
      }
    }

    // pack to bf16 pairs: pa0 = k 8g..8g+7, pa1 = k 32+8g..32+8g+7
    uint32_t pk[8];
    #pragma unroll
    for (int i = 0; i < 8; ++i) {
      float lo = p[i >> 1][(i & 1) * 2], hi = p[i >> 1][(i & 1) * 2 + 1];
      asm("v_cvt_pk_bf16_f32 %0, %1, %2" : "=v"(pk[i]) : "v"(lo), "v"(hi));
    }
    union PA { uint32_t u[4]; bf16x8 v; } a0, a1;
    #pragma unroll
    for (int i = 0; i < 4; ++i) { a0.u[i] = pk[i]; a1.u[i] = pk[4 + i]; }

    // PV
    #pragma unroll
    for (int dt = 0; dt < 4; ++dt) {
      bf16x8 vb0 = *(const bf16x8*)(vb + vro[dt] + ((g ^ vxr[dt]) << 4));
      bf16x8 vb1 = *(const bf16x8*)(vb + vro[dt] + (((4 + g) ^ vxr[dt]) << 4));
      acc_o[dt] = __builtin_amdgcn_mfma_f32_16x16x32_bf16(a0.v, vb0, acc_o[dt], 0, 0, 0);
      acc_o[dt] = __builtin_amdgcn_mfma_f32_16x16x32_bf16(a1.v, vb1, acc_o[dt], 0, 0, 0);
    }

    __syncthreads();
    cur ^= 1;
  }

  // full row sums: reduce over the 4 g-lanes holding the same q=c
  l_run += __shfl_xor(l_run, 16);
  l_run += __shfl_xor(l_run, 32);

  float inv[4];
  #pragma unroll
  for (int r = 0; r < 4; ++r)
    inv[r] = 1.0f / __shfl(l_run, g * 4 + r);

  #pragma unroll
  for (int dt = 0; dt < 4; ++dt)
    #pragma unroll
    for (int r = 0; r < 4; ++r) {
      int row = b * SDIM + qloc + g * 4 + r;
      vals[(size_t)row * EMB + h * HDIM + dt * 16 + c] = f2bf(acc_o[dt][r] * inv[r]);
    }
}

extern "C" void kernel_launch(void* const* d_in, const int* in_sizes, int n_in,
                              void* d_out, int out_size, void* d_ws, size_t ws_size,
                              hipStream_t stream) {
  const float* x     = (const float*)d_in[0];
  const int*   mask  = (const int*)d_in[1];
  const float* wts   = (const float*)d_in[2];
  const float* W_qkv = (const float*)d_in[3];
  const float* b_qkv = (const float*)d_in[4];
  const float* W_o   = (const float*)d_in[5];
  const float* b_o   = (const float*)d_in[6];
  float* out = (float*)d_out;

  char* ws = (char*)d_ws;
  u16* xb   = (u16*)(ws);                     //  8 MB x bf16
  u16* wqb  = (u16*)(ws + (8ull  << 20));     //  6 MB W_qkv bf16
  u16* wob  = (u16*)(ws + (14ull << 20));     //  2 MB W_o bf16
  u16* Qh   = (u16*)(ws + (16ull << 20));     //  8 MB [bh][s][64]
  u16* Kh   = (u16*)(ws + (24ull << 20));     //  8 MB [bh][s][64]
  u16* Vt   = (u16*)(ws + (32ull << 20));     //  8 MB [bh][64][s]
  u16* valb = (u16*)(ws + (40ull << 20));     //  8 MB attn out bf16
  u16* wm3b = (u16*)d_out;                    //  8 MB scratch in d_out (overwritten by gemm_bt)

  cvt3_kernel<<<2048, 256, 0, stream>>>(x, W_qkv, W_o, xb, wqb, wob);

  gemm_qkv_wm3<<<704, 512, 0, stream>>>(xb, wqb, b_qkv, Qh, Kh, Vt, mask, wts, wm3b);

  attn_kernel<<<1024, 256, 0, stream>>>(Qh, Kh, Vt, wm3b, valb);

  dim3 g3(32, 8);
  gemm_bt<<<g3, 256, 0, stream>>>(valb, wob, b_o, out, BATCH * SDIM, EMB, KDIM);
}